// Round 1
// baseline (473.171 us; speedup 1.0000x reference)
//
#include <hip/hip_runtime.h>
#include <stdint.h>

#define N_SRC  200000
#define N_DST0 50000
#define N_DST1 10000
#define E0_N   800000
#define E1_N   320000
#define IN_C   128
#define HID    64
#define H0_N   4
#define C0     256      // H0*HID
#define OUTC   40
#define NEG_SLOPE 0.2f
#define BN_EPS 1e-5f

typedef __attribute__((ext_vector_type(8))) short short8;
typedef __attribute__((ext_vector_type(4))) float f32x4;
typedef __attribute__((ext_vector_type(4))) unsigned short u16x4;

__device__ __forceinline__ float bf2f(unsigned short u){
  union{unsigned int i; float f;} v; v.i = ((unsigned int)u) << 16; return v.f;
}
__device__ __forceinline__ unsigned short f2bf(float f){
  union{float f; unsigned int i;} v; v.f = f;
  unsigned int u = v.i;
  unsigned int r = (u + 0x7FFFu + ((u >> 16) & 1u)) >> 16;
  return (unsigned short)r;
}
__device__ __forceinline__ float lrelu(float x){ return x > 0.f ? x : NEG_SLOPE * x; }

// ---------------- prep: transpose weights to bf16 [N][K] ----------------
__global__ void prep_w0(const float* __restrict__ W0, unsigned short* __restrict__ wt0){
  int idx = blockIdx.x * 256 + threadIdx.x;           // 256*128
  if (idx >= C0 * IN_C) return;
  int n = idx / IN_C, k = idx % IN_C;
  wt0[idx] = f2bf(W0[k * C0 + n]);
}
__global__ void prep_w1(const float* __restrict__ W1, unsigned short* __restrict__ w1t){
  int idx = blockIdx.x * 256 + threadIdx.x;           // 48*256
  if (idx >= 48 * C0) return;
  int n = idx / C0, k = idx % C0;
  w1t[idx] = (n < OUTC) ? f2bf(W1[k * OUTC + n]) : (unsigned short)0;
}

// ---------------- GEMM0: h0 = x @ W0 (bf16 out) + fused alpha_s/alpha_d ----------------
// grid (3125, 2), block 128 (2 waves). Block tile: 64 rows x 128 cols. Wave tile: 64x64.
__global__ __launch_bounds__(128) void gemm0_kernel(
    const float* __restrict__ x, const unsigned short* __restrict__ wt0,
    const float* __restrict__ att_s, const float* __restrict__ att_d,
    unsigned short* __restrict__ h0, float* __restrict__ as0, float* __restrict__ ad0)
{
  __shared__ __align__(16) unsigned short aT[64 * 136];
  __shared__ __align__(16) unsigned short wT[128 * 136];
  int tid = threadIdx.x;
  int r0 = blockIdx.x * 64;
  int c0 = blockIdx.y * 128;

  // stage A: x[r0..r0+64)[0..128) f32 -> bf16 LDS
  {
    const f32x4* x4 = (const f32x4*)(x + (size_t)r0 * IN_C);
    #pragma unroll
    for (int i = 0; i < 16; i++){
      int fi = tid + i * 128;            // 0..2047
      int row = fi >> 5, kq = fi & 31;
      f32x4 v = x4[fi];
      u16x4 b;
      #pragma unroll
      for (int j = 0; j < 4; j++) b[j] = f2bf(v[j]);
      *(u16x4*)&aT[row * 136 + kq * 4] = b;
    }
  }
  // stage W: wt0 rows c0..c0+128 (each 128 bf16)
  {
    const u16x4* w4 = (const u16x4*)(wt0 + (size_t)c0 * IN_C);
    #pragma unroll
    for (int i = 0; i < 32; i++){
      int fi = tid + i * 128;            // 0..4095
      int col = fi >> 5, kq = fi & 31;
      *(u16x4*)&wT[col * 136 + kq * 4] = w4[fi];
    }
  }
  __syncthreads();

  int w = tid >> 6, lane = tid & 63, lo = lane & 15, hi = lane >> 4;
  f32x4 zero4 = {0.f, 0.f, 0.f, 0.f};
  f32x4 acc[4][4];
  #pragma unroll
  for (int mf = 0; mf < 4; mf++)
    #pragma unroll
    for (int nf = 0; nf < 4; nf++) acc[mf][nf] = zero4;

  #pragma unroll
  for (int kf = 0; kf < 4; kf++){
    int kb = kf * 32 + hi * 8;
    short8 a[4], b[4];
    #pragma unroll
    for (int mf = 0; mf < 4; mf++) a[mf] = *(const short8*)&aT[(mf * 16 + lo) * 136 + kb];
    #pragma unroll
    for (int nf = 0; nf < 4; nf++) b[nf] = *(const short8*)&wT[(w * 64 + nf * 16 + lo) * 136 + kb];
    #pragma unroll
    for (int mf = 0; mf < 4; mf++)
      #pragma unroll
      for (int nf = 0; nf < 4; nf++)
        acc[mf][nf] = __builtin_amdgcn_mfma_f32_16x16x32_bf16(a[mf], b[nf], acc[mf][nf], 0, 0, 0);
  }

  int head = blockIdx.y * 2 + w;         // wave covers exactly one head (64 cols)
  int cb = c0 + w * 64;
  // C store (bf16)
  #pragma unroll
  for (int mf = 0; mf < 4; mf++)
    #pragma unroll
    for (int nf = 0; nf < 4; nf++)
      #pragma unroll
      for (int rg = 0; rg < 4; rg++){
        int row = r0 + mf * 16 + hi * 4 + rg;
        h0[(size_t)row * C0 + cb + nf * 16 + lo] = f2bf(acc[mf][nf][rg]);
      }
  // fused alpha: per-row dot with att vectors of this head
  float asv[4], adv[4];
  #pragma unroll
  for (int nf = 0; nf < 4; nf++){
    asv[nf] = att_s[head * HID + nf * 16 + lo];
    adv[nf] = att_d[head * HID + nf * 16 + lo];
  }
  #pragma unroll
  for (int mf = 0; mf < 4; mf++)
    #pragma unroll
    for (int rg = 0; rg < 4; rg++){
      float ps = 0.f, pd = 0.f;
      #pragma unroll
      for (int nf = 0; nf < 4; nf++){
        float v = acc[mf][nf][rg];
        ps += v * asv[nf]; pd += v * adv[nf];
      }
      #pragma unroll
      for (int m = 8; m >= 1; m >>= 1){
        ps += __shfl_xor(ps, m, 16);
        pd += __shfl_xor(pd, m, 16);
      }
      if (lo == 0){
        int row = r0 + mf * 16 + hi * 4 + rg;
        as0[row * H0_N + head] = ps;
        if (row < N_DST0) ad0[row * H0_N + head] = pd;
      }
    }
}

// ---------------- CSR build ----------------
__global__ void hist_kernel(const int* __restrict__ dst, int E, int* __restrict__ cnt){
  int e = blockIdx.x * 256 + threadIdx.x;
  if (e < E) atomicAdd(&cnt[dst[e]], 1);
}
__global__ void scanA(const int* __restrict__ cnt, int n, int* __restrict__ partials){
  __shared__ int s[256];
  int i = blockIdx.x * 256 + threadIdx.x;
  s[threadIdx.x] = (i < n) ? cnt[i] : 0;
  __syncthreads();
  for (int off = 128; off > 0; off >>= 1){
    if (threadIdx.x < off) s[threadIdx.x] += s[threadIdx.x + off];
    __syncthreads();
  }
  if (threadIdx.x == 0) partials[blockIdx.x] = s[0];
}
__global__ void scanB(int* __restrict__ partials, int nb){
  __shared__ int s[256];
  int t = threadIdx.x;
  int v = (t < nb) ? partials[t] : 0;
  s[t] = v; __syncthreads();
  for (int off = 1; off < 256; off <<= 1){
    int u = (t >= off) ? s[t - off] : 0;
    __syncthreads();
    s[t] += u;
    __syncthreads();
  }
  if (t < nb) partials[t] = s[t] - v;     // exclusive
}
__global__ void scanC(const int* __restrict__ cnt, int n, const int* __restrict__ partials,
                      int* __restrict__ row_ptr, int* __restrict__ cursor){
  __shared__ int s[256];
  int t = threadIdx.x; int i = blockIdx.x * 256 + t;
  int v = (i < n) ? cnt[i] : 0;
  s[t] = v; __syncthreads();
  for (int off = 1; off < 256; off <<= 1){
    int u = (t >= off) ? s[t - off] : 0;
    __syncthreads();
    s[t] += u;
    __syncthreads();
  }
  int excl = s[t] - v + partials[blockIdx.x];
  if (i < n){
    row_ptr[i] = excl; cursor[i] = excl;
    if (i == n - 1) row_ptr[n] = excl + v;
  }
}
__global__ void scatter_kernel(const int* __restrict__ src, const int* __restrict__ dst, int E,
                               int* __restrict__ cursor, int* __restrict__ col){
  int e = blockIdx.x * 256 + threadIdx.x;
  if (e < E){
    int pos = atomicAdd(&cursor[dst[e]], 1);
    col[pos] = src[e];
  }
}

// ---------------- agg0: per-dst softmax + weighted gather, 1 wave/dst ----------------
__global__ __launch_bounds__(256) void agg0_kernel(
    const unsigned short* __restrict__ h0, const float* __restrict__ as0, const float* __restrict__ ad0,
    const int* __restrict__ row_ptr, const int* __restrict__ col,
    const float* __restrict__ bias0, float* __restrict__ out0)
{
  int gid = blockIdx.x * 256 + threadIdx.x;
  int d = gid >> 6, t = gid & 63;
  if (d >= N_DST0) return;
  int rs = row_ptr[d], re = row_ptr[d + 1];
  f32x4 adv = ((const f32x4*)ad0)[d];
  f32x4 asd = ((const f32x4*)as0)[d];
  float es[4];
  #pragma unroll
  for (int h = 0; h < 4; h++) es[h] = lrelu(asd[h] + adv[h]);

  float m[4], z[4];
  #pragma unroll
  for (int h = 0; h < 4; h++){ m[h] = -1e30f; z[h] = 0.f; }
  for (int i = rs + t; i < re; i += 64){
    int s = col[i];
    f32x4 a4 = ((const f32x4*)as0)[s];
    #pragma unroll
    for (int h = 0; h < 4; h++){
      float e = lrelu(a4[h] + adv[h]);
      float M = fmaxf(m[h], e);
      z[h] = z[h] * __expf(m[h] - M) + __expf(e - M);
      m[h] = M;
    }
  }
  #pragma unroll
  for (int msk = 1; msk < 64; msk <<= 1){
    #pragma unroll
    for (int h = 0; h < 4; h++){
      float m2 = __shfl_xor(m[h], msk);
      float z2 = __shfl_xor(z[h], msk);
      float M = fmaxf(m[h], m2);
      z[h] = z[h] * __expf(m[h] - M) + z2 * __expf(m2 - M);
      m[h] = M;
    }
  }
  #pragma unroll
  for (int h = 0; h < 4; h++){
    float M = fmaxf(m[h], es[h]);
    z[h] = z[h] * __expf(m[h] - M) + __expf(es[h] - M);
    m[h] = M;
  }
  int ht = t >> 4;
  float mh = m[ht], rzh = 1.f / z[ht], adh = adv[ht];
  float acc0 = 0.f, acc1 = 0.f, acc2 = 0.f, acc3 = 0.f;
  for (int i = rs; i < re; i++){
    int s = col[i];
    float e = lrelu(as0[s * H0_N + ht] + adh);
    float p = __expf(e - mh) * rzh;
    u16x4 hv = *(const u16x4*)&h0[(size_t)s * C0 + t * 4];
    acc0 += bf2f(hv[0]) * p; acc1 += bf2f(hv[1]) * p;
    acc2 += bf2f(hv[2]) * p; acc3 += bf2f(hv[3]) * p;
  }
  {
    float p = __expf(es[ht] - mh) * rzh;
    u16x4 hv = *(const u16x4*)&h0[(size_t)d * C0 + t * 4];
    acc0 += bf2f(hv[0]) * p; acc1 += bf2f(hv[1]) * p;
    acc2 += bf2f(hv[2]) * p; acc3 += bf2f(hv[3]) * p;
  }
  f32x4 b4 = ((const f32x4*)bias0)[t];
  f32x4 o; o[0] = acc0 + b4[0]; o[1] = acc1 + b4[1]; o[2] = acc2 + b4[2]; o[3] = acc3 + b4[3];
  ((f32x4*)out0)[d * (C0 / 4) + t] = o;
}

// ---------------- BatchNorm stats ----------------
__global__ void bn_stats(const float* __restrict__ out0, float* __restrict__ gsum, float* __restrict__ gsq){
  int t = threadIdx.x;
  int r0 = blockIdx.x * 128;
  int rend = r0 + 128; if (rend > N_DST0) rend = N_DST0;
  float s = 0.f, q = 0.f;
  for (int r = r0; r < rend; r++){
    float v = out0[(size_t)r * C0 + t];
    s += v; q += v * v;
  }
  atomicAdd(&gsum[t], s);
  atomicAdd(&gsq[t], q);
}
__global__ void bn_final(const float* __restrict__ gsum, const float* __restrict__ gsq,
                         const float* __restrict__ gamma, const float* __restrict__ beta,
                         float* __restrict__ scaleb, float* __restrict__ shiftb){
  int t = threadIdx.x;
  float mu = gsum[t] * (1.f / N_DST0);
  float var = gsq[t] * (1.f / N_DST0) - mu * mu;
  float rs = rsqrtf(var + BN_EPS);
  float sc = gamma[t] * rs;
  scaleb[t] = sc;
  shiftb[t] = beta[t] - mu * sc;
}

// ---------------- GEMM1: h1 = relu(bn(out0)) @ W1 + fused alpha1 ----------------
// grid 196, block 256 (4 waves). Block tile: 256 rows x 48 cols (40 valid). K chunks of 64.
__global__ __launch_bounds__(256) void gemm1_kernel(
    const float* __restrict__ out0, const unsigned short* __restrict__ w1t,
    const float* __restrict__ scaleb, const float* __restrict__ shiftb,
    const float* __restrict__ att_s1, const float* __restrict__ att_d1,
    float* __restrict__ h1, float* __restrict__ as1, float* __restrict__ ad1)
{
  __shared__ __align__(16) unsigned short aT[256 * 72];
  __shared__ __align__(16) unsigned short wT[48 * 72];
  int tid = threadIdx.x;
  int r0 = blockIdx.x * 256;
  int w = tid >> 6, lane = tid & 63, lo = lane & 15, hi = lane >> 4;

  f32x4 zero4 = {0.f, 0.f, 0.f, 0.f};
  f32x4 acc[4][3];
  #pragma unroll
  for (int mf = 0; mf < 4; mf++)
    #pragma unroll
    for (int nf = 0; nf < 3; nf++) acc[mf][nf] = zero4;

  for (int kc = 0; kc < 4; kc++){
    if (kc) __syncthreads();
    // stage A chunk: rows r0..r0+256, k in [kc*64, kc*64+64), BN+ReLU applied, bf16
    #pragma unroll
    for (int i = 0; i < 16; i++){
      int fi = tid + i * 256;          // 0..4095
      int row = fi >> 4, kq = fi & 15;
      int r = r0 + row;
      f32x4 v = zero4;
      if (r < N_DST0) v = ((const f32x4*)out0)[(size_t)r * (C0 / 4) + kc * 16 + kq];
      f32x4 sc = ((const f32x4*)scaleb)[kc * 16 + kq];
      f32x4 sh = ((const f32x4*)shiftb)[kc * 16 + kq];
      u16x4 b;
      #pragma unroll
      for (int j = 0; j < 4; j++){
        float u = v[j] * sc[j] + sh[j];
        u = u > 0.f ? u : 0.f;
        b[j] = f2bf(u);
      }
      *(u16x4*)&aT[row * 72 + kq * 4] = b;
    }
    // stage W chunk: 48 x 64
    #pragma unroll
    for (int i = 0; i < 3; i++){
      int fi = tid + i * 256;          // 0..767
      int n = fi >> 4, kq = fi & 15;
      *(u16x4*)&wT[n * 72 + kq * 4] = ((const u16x4*)w1t)[n * 64 + kc * 16 + kq];
    }
    __syncthreads();
    #pragma unroll
    for (int kk = 0; kk < 2; kk++){
      int kb = kk * 32 + hi * 8;
      short8 a[4], b[3];
      #pragma unroll
      for (int mf = 0; mf < 4; mf++) a[mf] = *(const short8*)&aT[(w * 64 + mf * 16 + lo) * 72 + kb];
      #pragma unroll
      for (int nf = 0; nf < 3; nf++) b[nf] = *(const short8*)&wT[(nf * 16 + lo) * 72 + kb];
      #pragma unroll
      for (int mf = 0; mf < 4; mf++)
        #pragma unroll
        for (int nf = 0; nf < 3; nf++)
          acc[mf][nf] = __builtin_amdgcn_mfma_f32_16x16x32_bf16(a[mf], b[nf], acc[mf][nf], 0, 0, 0);
    }
  }

  // epilogue
  float asv[3], adv[3];
  #pragma unroll
  for (int nf = 0; nf < 3; nf++){
    int c = nf * 16 + lo;
    asv[nf] = (c < OUTC) ? att_s1[c] : 0.f;
    adv[nf] = (c < OUTC) ? att_d1[c] : 0.f;
  }
  #pragma unroll
  for (int mf = 0; mf < 4; mf++)
    #pragma unroll
    for (int rg = 0; rg < 4; rg++){
      int r = r0 + w * 64 + mf * 16 + hi * 4 + rg;
      float ps = 0.f, pd = 0.f;
      #pragma unroll
      for (int nf = 0; nf < 3; nf++){
        float v = acc[mf][nf][rg];
        int c = nf * 16 + lo;
        if (c < OUTC && r < N_DST0) h1[(size_t)r * OUTC + c] = v;
        ps += v * asv[nf]; pd += v * adv[nf];
      }
      #pragma unroll
      for (int m = 8; m >= 1; m >>= 1){
        ps += __shfl_xor(ps, m, 16);
        pd += __shfl_xor(pd, m, 16);
      }
      if (lo == 0 && r < N_DST0){
        as1[r] = ps;
        if (r < N_DST1) ad1[r] = pd;
      }
    }
}

// ---------------- agg1: per-dst softmax + gather + bias + log_softmax ----------------
__global__ __launch_bounds__(256) void agg1_kernel(
    const float* __restrict__ h1, const float* __restrict__ as1, const float* __restrict__ ad1,
    const int* __restrict__ row_ptr, const int* __restrict__ col,
    const float* __restrict__ bias1, float* __restrict__ out)
{
  int gid = blockIdx.x * 256 + threadIdx.x;
  int d = gid >> 6, t = gid & 63;
  if (d >= N_DST1) return;
  int rs = row_ptr[d], re = row_ptr[d + 1];
  float adv = ad1[d];
  float es = lrelu(as1[d] + adv);
  float m = -1e30f, z = 0.f;
  for (int i = rs + t; i < re; i += 64){
    float e = lrelu(as1[col[i]] + adv);
    float M = fmaxf(m, e);
    z = z * __expf(m - M) + __expf(e - M);
    m = M;
  }
  #pragma unroll
  for (int msk = 1; msk < 64; msk <<= 1){
    float m2 = __shfl_xor(m, msk);
    float z2 = __shfl_xor(z, msk);
    float M = fmaxf(m, m2);
    z = z * __expf(m - M) + z2 * __expf(m2 - M);
    m = M;
  }
  {
    float M = fmaxf(m, es);
    z = z * __expf(m - M) + __expf(es - M);
    m = M;
  }
  float rz = 1.f / z;
  float acc = 0.f;
  for (int i = rs; i < re; i++){
    int s = col[i];
    float p = __expf(lrelu(as1[s] + adv) - m) * rz;
    if (t < OUTC) acc += h1[(size_t)s * OUTC + t] * p;
  }
  {
    float p = __expf(es - m) * rz;
    if (t < OUTC) acc += h1[(size_t)d * OUTC + t] * p;
  }
  float v = acc + ((t < OUTC) ? bias1[t] : 0.f);
  float vm = (t < OUTC) ? v : -1e30f;
  #pragma unroll
  for (int msk = 1; msk < 64; msk <<= 1) vm = fmaxf(vm, __shfl_xor(vm, msk));
  float ex = (t < OUTC) ? __expf(v - vm) : 0.f;
  #pragma unroll
  for (int msk = 1; msk < 64; msk <<= 1) ex += __shfl_xor(ex, msk);
  if (t < OUTC) out[(size_t)d * OUTC + t] = v - vm - __logf(ex);
}

// ---------------- launch ----------------
extern "C" void kernel_launch(void* const* d_in, const int* in_sizes, int n_in,
                              void* d_out, int out_size, void* d_ws, size_t ws_size,
                              hipStream_t stream)
{
  const float* x        = (const float*)d_in[0];
  const float* W0       = (const float*)d_in[1];
  const float* att_src0 = (const float*)d_in[2];
  const float* att_dst0 = (const float*)d_in[3];
  const float* bias0    = (const float*)d_in[4];
  const float* gamma0   = (const float*)d_in[5];
  const float* beta0    = (const float*)d_in[6];
  const float* W1       = (const float*)d_in[7];
  const float* att_src1 = (const float*)d_in[8];
  const float* att_dst1 = (const float*)d_in[9];
  const float* bias1    = (const float*)d_in[10];
  const int* esrc0 = (const int*)d_in[11];
  const int* edst0 = (const int*)d_in[12];
  const int* esrc1 = (const int*)d_in[13];
  const int* edst1 = (const int*)d_in[14];
  float* out = (float*)d_out;

  char* p = (char*)d_ws;
  auto alloc = [&](size_t b) -> char* {
    char* r = p; p += (b + 255) & ~(size_t)255; return r;
  };
  unsigned short* h0  = (unsigned short*)alloc((size_t)N_SRC * C0 * 2);     // 102.4 MB
  float* out0         = (float*)alloc((size_t)N_DST0 * C0 * 4);             // 51.2 MB
  unsigned short* wt0 = (unsigned short*)alloc((size_t)C0 * IN_C * 2);
  unsigned short* w1t = (unsigned short*)alloc((size_t)48 * C0 * 2);
  float* as0          = (float*)alloc((size_t)N_SRC * H0_N * 4);
  float* ad0          = (float*)alloc((size_t)N_DST0 * H0_N * 4);
  float* h1           = (float*)alloc((size_t)N_DST0 * OUTC * 4);
  float* as1          = (float*)alloc((size_t)N_DST0 * 4);
  float* ad1          = (float*)alloc((size_t)N_DST1 * 4);
  float* scaleb       = (float*)alloc((size_t)C0 * 4);
  float* shiftb       = (float*)alloc((size_t)C0 * 4);
  int* row_ptr0       = (int*)alloc((size_t)(N_DST0 + 1) * 4);
  int* cursor0        = (int*)alloc((size_t)N_DST0 * 4);
  int* col0           = (int*)alloc((size_t)E0_N * 4);
  int* row_ptr1       = (int*)alloc((size_t)(N_DST1 + 1) * 4);
  int* cursor1        = (int*)alloc((size_t)N_DST1 * 4);
  int* col1           = (int*)alloc((size_t)E1_N * 4);
  int* partials       = (int*)alloc((size_t)256 * 4);
  // contiguous zero zone
  char* zbase = p;
  int* cnt0   = (int*)alloc((size_t)N_DST0 * 4);
  int* cnt1   = (int*)alloc((size_t)N_DST1 * 4);
  float* gsum = (float*)alloc((size_t)C0 * 4);
  float* gsq  = (float*)alloc((size_t)C0 * 4);
  size_t zspan = (size_t)(p - zbase);
  hipMemsetAsync(zbase, 0, zspan, stream);

  prep_w0<<<dim3((C0 * IN_C) / 256), 256, 0, stream>>>(W0, wt0);
  prep_w1<<<dim3((48 * C0) / 256), 256, 0, stream>>>(W1, w1t);

  gemm0_kernel<<<dim3(N_SRC / 64, 2), 128, 0, stream>>>(x, wt0, att_src0, att_dst0, h0, as0, ad0);

  hist_kernel<<<dim3(E0_N / 256), 256, 0, stream>>>(edst0, E0_N, cnt0);
  scanA<<<dim3(196), 256, 0, stream>>>(cnt0, N_DST0, partials);
  scanB<<<1, 256, 0, stream>>>(partials, 196);
  scanC<<<dim3(196), 256, 0, stream>>>(cnt0, N_DST0, partials, row_ptr0, cursor0);
  scatter_kernel<<<dim3(E0_N / 256), 256, 0, stream>>>(esrc0, edst0, E0_N, cursor0, col0);

  agg0_kernel<<<dim3(N_DST0 / 4), 256, 0, stream>>>(h0, as0, ad0, row_ptr0, col0, bias0, out0);

  bn_stats<<<dim3((N_DST0 + 127) / 128), 256, 0, stream>>>(out0, gsum, gsq);
  bn_final<<<1, 256, 0, stream>>>(gsum, gsq, gamma0, beta0, scaleb, shiftb);

  gemm1_kernel<<<dim3((N_DST0 + 255) / 256), 256, 0, stream>>>(out0, w1t, scaleb, shiftb,
                                                               att_src1, att_dst1, h1, as1, ad1);

  hist_kernel<<<dim3(E1_N / 256), 256, 0, stream>>>(edst1, E1_N, cnt1);
  scanA<<<dim3(40), 256, 0, stream>>>(cnt1, N_DST1, partials);
  scanB<<<1, 256, 0, stream>>>(partials, 40);
  scanC<<<dim3(40), 256, 0, stream>>>(cnt1, N_DST1, partials, row_ptr1, cursor1);
  scatter_kernel<<<dim3(E1_N / 256), 256, 0, stream>>>(esrc1, edst1, E1_N, cursor1, col1);

  agg1_kernel<<<dim3(N_DST1 / 4), 256, 0, stream>>>(h1, as1, ad1, row_ptr1, col1, bias1, out);
}

// Round 2
// 380.657 us; speedup vs baseline: 1.2430x; 1.2430x over previous
//
#include <hip/hip_runtime.h>
#include <stdint.h>

#define N_SRC  200000
#define N_DST0 50000
#define N_DST1 10000
#define E0_N   800000
#define E1_N   320000
#define IN_C   128
#define HID    64
#define H0_N   4
#define C0     256      // H0*HID
#define OUTC   40
#define H1W    48       // padded h1 width
#define NEG_SLOPE 0.2f
#define BN_EPS 1e-5f

typedef __attribute__((ext_vector_type(8))) short short8;
typedef __attribute__((ext_vector_type(4))) float f32x4;
typedef __attribute__((ext_vector_type(4))) unsigned short u16x4;

__device__ __forceinline__ float bf2f(unsigned short u){
  union{unsigned int i; float f;} v; v.i = ((unsigned int)u) << 16; return v.f;
}
__device__ __forceinline__ unsigned short f2bf(float f){   // RNE (weights only)
  union{float f; unsigned int i;} v; v.f = f;
  unsigned int u = v.i;
  unsigned int r = (u + 0x7FFFu + ((u >> 16) & 1u)) >> 16;
  return (unsigned short)r;
}
// truncate-pack two f32 -> one u32 of 2 bf16 (compiler emits v_perm)
__device__ __forceinline__ unsigned int pkt(float a, float b){
  return (__float_as_uint(a) >> 16) | (__float_as_uint(b) & 0xFFFF0000u);
}
__device__ __forceinline__ unsigned short tbf(float f){
  return (unsigned short)(__float_as_uint(f) >> 16);
}
__device__ __forceinline__ float lrelu(float x){ return x > 0.f ? x : NEG_SLOPE * x; }

// ---------------- prep: weights ----------------
__global__ void prep_w0(const float* __restrict__ W0, unsigned short* __restrict__ wt0){
  int idx = blockIdx.x * 256 + threadIdx.x;           // 256*128
  if (idx >= C0 * IN_C) return;
  int n = idx / IN_C, k = idx % IN_C;
  wt0[idx] = f2bf(W0[k * C0 + n]);
}
__global__ void prep_w1(const float* __restrict__ W1, unsigned short* __restrict__ w1t){
  int idx = blockIdx.x * 256 + threadIdx.x;           // 48*256
  if (idx >= H1W * C0) return;
  int n = idx / C0, k = idx % C0;
  w1t[idx] = (n < OUTC) ? f2bf(W1[k * OUTC + n]) : (unsigned short)0;
}
// WA0[8][128]: col j<4 = W0 . att_src0[h], j>=4 = W0 . att_dst0[h]
// WA1[2][256]: W1 . att_src1 / att_dst1
__global__ void prep_wa(const float* __restrict__ W0, const float* __restrict__ as0a, const float* __restrict__ ad0a,
                        const float* __restrict__ W1, const float* __restrict__ as1a, const float* __restrict__ ad1a,
                        unsigned short* __restrict__ waG, unsigned short* __restrict__ wa1G){
  int idx = blockIdx.x * 256 + threadIdx.x;
  if (idx < 1024){
    int k = idx >> 3, j = idx & 7, h = j & 3;
    const float* att = (j < 4) ? as0a : ad0a;
    float s = 0.f;
    #pragma unroll
    for (int c = 0; c < HID; c++) s += W0[k * C0 + h * HID + c] * att[h * HID + c];
    waG[j * IN_C + k] = f2bf(s);
  } else if (idx < 1024 + 512){
    int r = idx - 1024; int k = r >> 1, j = r & 1;
    const float* att = j ? ad1a : as1a;
    float s = 0.f;
    #pragma unroll
    for (int c = 0; c < OUTC; c++) s += W1[k * OUTC + c] * att[c];
    wa1G[j * C0 + k] = f2bf(s);
  }
}

// ---------------- GEMM0: h0 = x @ W0 (bf16) + alpha via WA-MFMA ----------------
// grid 1563, block 512 (8 waves as 2x4). Tile 128 rows x 256 cols, K=128 one-shot.
__global__ __launch_bounds__(512) void gemm0_kernel(
    const float* __restrict__ x, const unsigned short* __restrict__ wt0,
    const unsigned short* __restrict__ waG,
    unsigned short* __restrict__ h0, float* __restrict__ as0, float* __restrict__ ad0)
{
  __shared__ __align__(16) unsigned short aT[128 * 136];
  __shared__ __align__(16) unsigned short wT[256 * 136];
  __shared__ __align__(16) unsigned short waT[16 * 136];
  int tid = threadIdx.x;
  int r0 = blockIdx.x * 128;

  // stage A: 128 rows x 128 K (f32 -> bf16 trunc)
  #pragma unroll
  for (int i = 0; i < 8; i++){
    int fi = tid + i * 512;            // 0..4095
    int row = fi >> 5, q = fi & 31;
    int r = r0 + row;
    f32x4 v = {0.f, 0.f, 0.f, 0.f};
    if (r < N_SRC) v = ((const f32x4*)x)[(size_t)r * 32 + q];
    uint2 pk; pk.x = pkt(v[0], v[1]); pk.y = pkt(v[2], v[3]);
    *(uint2*)&aT[row * 136 + q * 4] = pk;
  }
  // stage W: 256 x 128 bf16
  #pragma unroll
  for (int i = 0; i < 16; i++){
    int fi = tid + i * 512;            // 0..8191
    int row = fi >> 5, q = fi & 31;
    *(u16x4*)&wT[row * 136 + q * 4] = ((const u16x4*)wt0)[row * 32 + q];
  }
  // stage WA: rows 0..7 data, 8..15 zero
  {
    int row = tid >> 5, q = tid & 31;
    if (tid < 512){
      u16x4 v = {0,0,0,0};
      if (row < 8) v = ((const u16x4*)waG)[row * 32 + q];
      *(u16x4*)&waT[row * 136 + q * 4] = v;
    }
  }
  __syncthreads();

  int w = tid >> 6, lane = tid & 63, lo = lane & 15, hi = lane >> 4;
  int wr = w >> 2, wc = w & 3;
  f32x4 zero4 = {0.f, 0.f, 0.f, 0.f};
  f32x4 acc[4][4], acc_a[4];
  #pragma unroll
  for (int mf = 0; mf < 4; mf++){
    acc_a[mf] = zero4;
    #pragma unroll
    for (int nf = 0; nf < 4; nf++) acc[mf][nf] = zero4;
  }

  #pragma unroll
  for (int kf = 0; kf < 4; kf++){
    int kb = kf * 32 + hi * 8;
    short8 a[4], b[4];
    #pragma unroll
    for (int mf = 0; mf < 4; mf++) a[mf] = *(const short8*)&aT[(wr * 64 + mf * 16 + lo) * 136 + kb];
    #pragma unroll
    for (int nf = 0; nf < 4; nf++) b[nf] = *(const short8*)&wT[(wc * 64 + nf * 16 + lo) * 136 + kb];
    #pragma unroll
    for (int mf = 0; mf < 4; mf++)
      #pragma unroll
      for (int nf = 0; nf < 4; nf++)
        acc[mf][nf] = __builtin_amdgcn_mfma_f32_16x16x32_bf16(a[mf], b[nf], acc[mf][nf], 0, 0, 0);
    if (wc == 0){
      short8 wab = *(const short8*)&waT[lo * 136 + kb];
      #pragma unroll
      for (int mf = 0; mf < 4; mf++)
        acc_a[mf] = __builtin_amdgcn_mfma_f32_16x16x32_bf16(a[mf], wab, acc_a[mf], 0, 0, 0);
    }
  }

  // store h0 (bf16 trunc, scattered 2B)
  #pragma unroll
  for (int mf = 0; mf < 4; mf++)
    #pragma unroll
    for (int rg = 0; rg < 4; rg++){
      int row = r0 + wr * 64 + mf * 16 + hi * 4 + rg;
      if (row < N_SRC){
        #pragma unroll
        for (int nf = 0; nf < 4; nf++)
          h0[(size_t)row * C0 + wc * 64 + nf * 16 + lo] = tbf(acc[mf][nf][rg]);
      }
    }
  // store alpha (cols 0..3 = as, 4..7 = ad)
  if (wc == 0 && lo < 8){
    #pragma unroll
    for (int mf = 0; mf < 4; mf++)
      #pragma unroll
      for (int rg = 0; rg < 4; rg++){
        int row = r0 + wr * 64 + mf * 16 + hi * 4 + rg;
        float v = acc_a[mf][rg];
        if (lo < 4){ if (row < N_SRC) as0[row * H0_N + lo] = v; }
        else if (row < N_DST0) ad0[row * H0_N + (lo - 4)] = v;
      }
  }
}

// ---------------- CSR build ----------------
__global__ void hist_kernel(const int* __restrict__ dst, int E, int* __restrict__ cnt){
  int e = blockIdx.x * 256 + threadIdx.x;
  if (e < E) atomicAdd(&cnt[dst[e]], 1);
}
__global__ void scanA(const int* __restrict__ cnt, int n, int* __restrict__ partials){
  __shared__ int s[256];
  int i = blockIdx.x * 256 + threadIdx.x;
  s[threadIdx.x] = (i < n) ? cnt[i] : 0;
  __syncthreads();
  for (int off = 128; off > 0; off >>= 1){
    if (threadIdx.x < off) s[threadIdx.x] += s[threadIdx.x + off];
    __syncthreads();
  }
  if (threadIdx.x == 0) partials[blockIdx.x] = s[0];
}
__global__ void scanB(int* __restrict__ partials, int nb){
  __shared__ int s[256];
  int t = threadIdx.x;
  int v = (t < nb) ? partials[t] : 0;
  s[t] = v; __syncthreads();
  for (int off = 1; off < 256; off <<= 1){
    int u = (t >= off) ? s[t - off] : 0;
    __syncthreads();
    s[t] += u;
    __syncthreads();
  }
  if (t < nb) partials[t] = s[t] - v;     // exclusive
}
__global__ void scanC(const int* __restrict__ cnt, int n, const int* __restrict__ partials,
                      int* __restrict__ row_ptr, int* __restrict__ cursor){
  __shared__ int s[256];
  int t = threadIdx.x; int i = blockIdx.x * 256 + t;
  int v = (i < n) ? cnt[i] : 0;
  s[t] = v; __syncthreads();
  for (int off = 1; off < 256; off <<= 1){
    int u = (t >= off) ? s[t - off] : 0;
    __syncthreads();
    s[t] += u;
    __syncthreads();
  }
  int excl = s[t] - v + partials[blockIdx.x];
  if (i < n){
    row_ptr[i] = excl; cursor[i] = excl;
    if (i == n - 1) row_ptr[n] = excl + v;
  }
}
__global__ void scatter_kernel(const int* __restrict__ src, const int* __restrict__ dst, int E,
                               int* __restrict__ cursor, int* __restrict__ col){
  int e = blockIdx.x * 256 + threadIdx.x;
  if (e < E){
    int pos = atomicAdd(&cursor[dst[e]], 1);
    col[pos] = src[e];
  }
}

// ---------------- agg0: max-only pass + chunked LDS alphas + gather ----------------
__global__ __launch_bounds__(256) void agg0_kernel(
    const unsigned short* __restrict__ h0, const float* __restrict__ as0, const float* __restrict__ ad0,
    const int* __restrict__ row_ptr, const int* __restrict__ col,
    const float* __restrict__ bias0, unsigned short* __restrict__ out0)
{
  __shared__ f32x4 sp[4][64];
  __shared__ int   sc[4][64];
  int gid = blockIdx.x * 256 + threadIdx.x;
  int w = threadIdx.x >> 6;
  int d = gid >> 6, t = gid & 63;
  if (d >= N_DST0) return;
  int rs = row_ptr[d], re = row_ptr[d + 1];
  f32x4 adv = ((const f32x4*)ad0)[d];
  f32x4 asd = ((const f32x4*)as0)[d];
  f32x4 es;
  #pragma unroll
  for (int h = 0; h < 4; h++) es[h] = lrelu(asd[h] + adv[h]);

  // phase 1: max only
  f32x4 m4 = {-1e30f, -1e30f, -1e30f, -1e30f};
  for (int i = rs + t; i < re; i += 64){
    int s = col[i];
    f32x4 a4 = ((const f32x4*)as0)[s];
    #pragma unroll
    for (int h = 0; h < 4; h++) m4[h] = fmaxf(m4[h], lrelu(a4[h] + adv[h]));
  }
  #pragma unroll
  for (int msk = 1; msk < 64; msk <<= 1){
    #pragma unroll
    for (int h = 0; h < 4; h++) m4[h] = fmaxf(m4[h], __shfl_xor(m4[h], msk));
  }
  #pragma unroll
  for (int h = 0; h < 4; h++) m4[h] = fmaxf(m4[h], es[h]);

  int ht = t >> 4;
  float acc0 = 0.f, acc1 = 0.f, acc2 = 0.f, acc3 = 0.f;
  f32x4 zl = {0.f, 0.f, 0.f, 0.f};
  const float* spf = (const float*)sp;

  for (int c = rs; c < re; c += 64){
    int i = c + t;
    if (i < re){
      int s = col[i];
      f32x4 a4 = ((const f32x4*)as0)[s];
      f32x4 q4;
      #pragma unroll
      for (int h = 0; h < 4; h++){
        q4[h] = __expf(lrelu(a4[h] + adv[h]) - m4[h]);
        zl[h] += q4[h];
      }
      sp[w][t] = q4; sc[w][t] = s;
    }
    asm volatile("s_waitcnt lgkmcnt(0)" ::: "memory");
    int n = re - c; if (n > 64) n = 64;
    for (int j = 0; j < n; j++){
      int s = sc[w][j];
      float p = spf[(w * 64 + j) * 4 + ht];
      u16x4 hv = *(const u16x4*)&h0[(size_t)s * C0 + t * 4];
      acc0 += bf2f(hv[0]) * p; acc1 += bf2f(hv[1]) * p;
      acc2 += bf2f(hv[2]) * p; acc3 += bf2f(hv[3]) * p;
    }
    asm volatile("s_waitcnt lgkmcnt(0)" ::: "memory");
  }
  // z reduce + self loop
  #pragma unroll
  for (int msk = 1; msk < 64; msk <<= 1){
    #pragma unroll
    for (int h = 0; h < 4; h++) zl[h] += __shfl_xor(zl[h], msk);
  }
  #pragma unroll
  for (int h = 0; h < 4; h++) zl[h] += __expf(es[h] - m4[h]);
  float qs = __expf(es[ht] - m4[ht]);
  {
    u16x4 hv = *(const u16x4*)&h0[(size_t)d * C0 + t * 4];
    acc0 += bf2f(hv[0]) * qs; acc1 += bf2f(hv[1]) * qs;
    acc2 += bf2f(hv[2]) * qs; acc3 += bf2f(hv[3]) * qs;
  }
  float rz = 1.f / zl[ht];
  f32x4 b4 = ((const f32x4*)bias0)[t];
  uint2 pk;
  pk.x = pkt(acc0 * rz + b4[0], acc1 * rz + b4[1]);
  pk.y = pkt(acc2 * rz + b4[2], acc3 * rz + b4[3]);
  ((uint2*)out0)[(size_t)d * 64 + t] = pk;
}

// ---------------- BatchNorm stats (bf16 input) ----------------
__global__ void bn_stats(const unsigned short* __restrict__ out0, float* __restrict__ gsum, float* __restrict__ gsq){
  int t = threadIdx.x;
  int r0 = blockIdx.x * 128;
  int rend = r0 + 128; if (rend > N_DST0) rend = N_DST0;
  float s = 0.f, q = 0.f;
  for (int r = r0; r < rend; r++){
    float v = bf2f(out0[(size_t)r * C0 + t]);
    s += v; q += v * v;
  }
  atomicAdd(&gsum[t], s);
  atomicAdd(&gsq[t], q);
}
__global__ void bn_final(const float* __restrict__ gsum, const float* __restrict__ gsq,
                         const float* __restrict__ gamma, const float* __restrict__ beta,
                         float* __restrict__ scaleb, float* __restrict__ shiftb){
  int t = threadIdx.x;
  float mu = gsum[t] * (1.f / N_DST0);
  float var = gsq[t] * (1.f / N_DST0) - mu * mu;
  float rs = rsqrtf(var + BN_EPS);
  float sc = gamma[t] * rs;
  scaleb[t] = sc;
  shiftb[t] = beta[t] - mu * sc;
}

// ---------------- GEMM1: h1 = relu(bn(out0)) @ W1 + alpha via WA1-MFMA ----------------
__global__ __launch_bounds__(256) void gemm1_kernel(
    const unsigned short* __restrict__ out0, const unsigned short* __restrict__ w1t,
    const unsigned short* __restrict__ wa1G,
    const float* __restrict__ scaleb, const float* __restrict__ shiftb,
    float* __restrict__ h1, float* __restrict__ as1, float* __restrict__ ad1)
{
  __shared__ __align__(16) unsigned short aT[256 * 72];
  __shared__ __align__(16) unsigned short wT[48 * 72];
  __shared__ __align__(16) unsigned short wa1T[16 * 72];
  int tid = threadIdx.x;
  int r0 = blockIdx.x * 256;
  int w = tid >> 6, lane = tid & 63, lo = lane & 15, hi = lane >> 4;

  f32x4 zero4 = {0.f, 0.f, 0.f, 0.f};
  f32x4 acc[4][3], acc_a[4];
  #pragma unroll
  for (int mf = 0; mf < 4; mf++){
    acc_a[mf] = zero4;
    #pragma unroll
    for (int nf = 0; nf < 3; nf++) acc[mf][nf] = zero4;
  }

  for (int kc = 0; kc < 4; kc++){
    if (kc) __syncthreads();
    // stage A chunk (BN + ReLU applied)
    #pragma unroll
    for (int i = 0; i < 16; i++){
      int fi = tid + i * 256;          // 0..4095
      int row = fi >> 4, kq = fi & 15;
      int r = r0 + row;
      u16x4 v = {0,0,0,0};
      if (r < N_DST0) v = ((const u16x4*)out0)[(size_t)r * 64 + kc * 16 + kq];
      f32x4 sc4 = ((const f32x4*)scaleb)[kc * 16 + kq];
      f32x4 sh4 = ((const f32x4*)shiftb)[kc * 16 + kq];
      float f[4];
      #pragma unroll
      for (int j = 0; j < 4; j++){
        float u = bf2f(v[j]) * sc4[j] + sh4[j];
        f[j] = u > 0.f ? u : 0.f;
      }
      uint2 pk; pk.x = pkt(f[0], f[1]); pk.y = pkt(f[2], f[3]);
      *(uint2*)&aT[row * 72 + kq * 4] = pk;
    }
    // stage W chunk: 48 x 64
    #pragma unroll
    for (int i = 0; i < 3; i++){
      int fi = tid + i * 256;          // 0..767
      int n = fi >> 4, kq = fi & 15;
      *(u16x4*)&wT[n * 72 + kq * 4] = ((const u16x4*)w1t)[n * 64 + kc * 16 + kq];
    }
    // stage WA1 chunk: rows 0..1 data, rest zero
    {
      int n = tid >> 4, kq = tid & 15;
      u16x4 v = {0,0,0,0};
      if (n < 2) v = ((const u16x4*)wa1G)[n * 64 + kc * 16 + kq];
      *(u16x4*)&wa1T[n * 72 + kq * 4] = v;
    }
    __syncthreads();
    #pragma unroll
    for (int kk = 0; kk < 2; kk++){
      int kb = kk * 32 + hi * 8;
      short8 a[4], b[3];
      #pragma unroll
      for (int mf = 0; mf < 4; mf++) a[mf] = *(const short8*)&aT[(w * 64 + mf * 16 + lo) * 72 + kb];
      #pragma unroll
      for (int nf = 0; nf < 3; nf++) b[nf] = *(const short8*)&wT[(nf * 16 + lo) * 72 + kb];
      short8 wab = *(const short8*)&wa1T[lo * 72 + kb];
      #pragma unroll
      for (int mf = 0; mf < 4; mf++){
        #pragma unroll
        for (int nf = 0; nf < 3; nf++)
          acc[mf][nf] = __builtin_amdgcn_mfma_f32_16x16x32_bf16(a[mf], b[nf], acc[mf][nf], 0, 0, 0);
        acc_a[mf] = __builtin_amdgcn_mfma_f32_16x16x32_bf16(a[mf], wab, acc_a[mf], 0, 0, 0);
      }
    }
  }

  // epilogue: h1 (48-wide, cols 40..47 = 0 from padded W) + alpha
  #pragma unroll
  for (int mf = 0; mf < 4; mf++)
    #pragma unroll
    for (int rg = 0; rg < 4; rg++){
      int r = r0 + w * 64 + mf * 16 + hi * 4 + rg;
      if (r < N_DST0){
        #pragma unroll
        for (int nf = 0; nf < 3; nf++)
          h1[(size_t)r * H1W + nf * 16 + lo] = acc[mf][nf][rg];
        if (lo == 0) as1[r] = acc_a[mf][rg];
        else if (lo == 1 && r < N_DST1) ad1[r] = acc_a[mf][rg];
      }
    }
}

// ---------------- agg1: max pass + chunked LDS alphas + gather + log_softmax ----------------
__global__ __launch_bounds__(256) void agg1_kernel(
    const float* __restrict__ h1, const float* __restrict__ as1, const float* __restrict__ ad1,
    const int* __restrict__ row_ptr, const int* __restrict__ col,
    const float* __restrict__ bias1, float* __restrict__ out)
{
  __shared__ float sp1[4][64];
  __shared__ int   sc1[4][64];
  int gid = blockIdx.x * 256 + threadIdx.x;
  int w = threadIdx.x >> 6;
  int d = gid >> 6, t = gid & 63;
  if (d >= N_DST1) return;
  int rs = row_ptr[d], re = row_ptr[d + 1];
  float adv = ad1[d];
  float es = lrelu(as1[d] + adv);
  float m = -1e30f;
  for (int i = rs + t; i < re; i += 64) m = fmaxf(m, lrelu(as1[col[i]] + adv));
  #pragma unroll
  for (int msk = 1; msk < 64; msk <<= 1) m = fmaxf(m, __shfl_xor(m, msk));
  m = fmaxf(m, es);

  bool tl = (t < H1W);
  float zl = 0.f, acc = 0.f;
  for (int c = rs; c < re; c += 64){
    int i = c + t;
    if (i < re){
      int s = col[i];
      float q = __expf(lrelu(as1[s] + adv) - m);
      zl += q;
      sp1[w][t] = q; sc1[w][t] = s;
    }
    asm volatile("s_waitcnt lgkmcnt(0)" ::: "memory");
    int n = re - c; if (n > 64) n = 64;
    for (int j = 0; j < n; j++){
      int s = sc1[w][j];
      float p = sp1[w][j];
      float hv = tl ? h1[(size_t)s * H1W + t] : 0.f;
      acc += p * hv;
    }
    asm volatile("s_waitcnt lgkmcnt(0)" ::: "memory");
  }
  #pragma unroll
  for (int msk = 1; msk < 64; msk <<= 1) zl += __shfl_xor(zl, msk);
  float qs = __expf(es - m);
  float z = zl + qs;
  float hs = tl ? h1[(size_t)d * H1W + t] : 0.f;
  acc = (acc + qs * hs) / z;
  float v = acc + ((t < OUTC) ? bias1[t] : 0.f);
  float vm = (t < OUTC) ? v : -1e30f;
  #pragma unroll
  for (int msk = 1; msk < 64; msk <<= 1) vm = fmaxf(vm, __shfl_xor(vm, msk));
  float ex = (t < OUTC) ? __expf(v - vm) : 0.f;
  #pragma unroll
  for (int msk = 1; msk < 64; msk <<= 1) ex += __shfl_xor(ex, msk);
  if (t < OUTC) out[(size_t)d * OUTC + t] = v - vm - __logf(ex);
}

// ---------------- launch ----------------
extern "C" void kernel_launch(void* const* d_in, const int* in_sizes, int n_in,
                              void* d_out, int out_size, void* d_ws, size_t ws_size,
                              hipStream_t stream)
{
  const float* x        = (const float*)d_in[0];
  const float* W0       = (const float*)d_in[1];
  const float* att_src0 = (const float*)d_in[2];
  const float* att_dst0 = (const float*)d_in[3];
  const float* bias0    = (const float*)d_in[4];
  const float* gamma0   = (const float*)d_in[5];
  const float* beta0    = (const float*)d_in[6];
  const float* W1       = (const float*)d_in[7];
  const float* att_src1 = (const float*)d_in[8];
  const float* att_dst1 = (const float*)d_in[9];
  const float* bias1    = (const float*)d_in[10];
  const int* esrc0 = (const int*)d_in[11];
  const int* edst0 = (const int*)d_in[12];
  const int* esrc1 = (const int*)d_in[13];
  const int* edst1 = (const int*)d_in[14];
  float* out = (float*)d_out;

  char* p = (char*)d_ws;
  auto alloc = [&](size_t b) -> char* {
    char* r = p; p += (b + 255) & ~(size_t)255; return r;
  };
  unsigned short* h0   = (unsigned short*)alloc((size_t)N_SRC * C0 * 2);    // 102.4 MB
  unsigned short* out0 = (unsigned short*)alloc((size_t)N_DST0 * C0 * 2);   // 25.6 MB
  unsigned short* wt0  = (unsigned short*)alloc((size_t)C0 * IN_C * 2);
  unsigned short* w1t  = (unsigned short*)alloc((size_t)H1W * C0 * 2);
  unsigned short* waG  = (unsigned short*)alloc((size_t)8 * IN_C * 2);
  unsigned short* wa1G = (unsigned short*)alloc((size_t)2 * C0 * 2);
  float* as0          = (float*)alloc((size_t)N_SRC * H0_N * 4);
  float* ad0          = (float*)alloc((size_t)N_DST0 * H0_N * 4);
  float* h1           = (float*)alloc((size_t)N_DST0 * H1W * 4);
  float* as1          = (float*)alloc((size_t)N_DST0 * 4);
  float* ad1          = (float*)alloc((size_t)N_DST1 * 4);
  float* scaleb       = (float*)alloc((size_t)C0 * 4);
  float* shiftb       = (float*)alloc((size_t)C0 * 4);
  int* row_ptr0       = (int*)alloc((size_t)(N_DST0 + 1) * 4);
  int* cursor0        = (int*)alloc((size_t)N_DST0 * 4);
  int* col0           = (int*)alloc((size_t)E0_N * 4);
  int* row_ptr1       = (int*)alloc((size_t)(N_DST1 + 1) * 4);
  int* cursor1        = (int*)alloc((size_t)N_DST1 * 4);
  int* col1           = (int*)alloc((size_t)E1_N * 4);
  int* partials       = (int*)alloc((size_t)256 * 4);
  // contiguous zero zone
  char* zbase = p;
  int* cnt0   = (int*)alloc((size_t)N_DST0 * 4);
  int* cnt1   = (int*)alloc((size_t)N_DST1 * 4);
  float* gsum = (float*)alloc((size_t)C0 * 4);
  float* gsq  = (float*)alloc((size_t)C0 * 4);
  size_t zspan = (size_t)(p - zbase);
  hipMemsetAsync(zbase, 0, zspan, stream);

  prep_w0<<<dim3((C0 * IN_C) / 256), 256, 0, stream>>>(W0, wt0);
  prep_w1<<<dim3((H1W * C0) / 256), 256, 0, stream>>>(W1, w1t);
  prep_wa<<<dim3(6), 256, 0, stream>>>(W0, att_src0, att_dst0, W1, att_src1, att_dst1, waG, wa1G);

  // CSR graph 0 (before gemm0 so h0 stays hot in L3 for agg0)
  hist_kernel<<<dim3(E0_N / 256), 256, 0, stream>>>(edst0, E0_N, cnt0);
  scanA<<<dim3(196), 256, 0, stream>>>(cnt0, N_DST0, partials);
  scanB<<<1, 256, 0, stream>>>(partials, 196);
  scanC<<<dim3(196), 256, 0, stream>>>(cnt0, N_DST0, partials, row_ptr0, cursor0);
  scatter_kernel<<<dim3(E0_N / 256), 256, 0, stream>>>(esrc0, edst0, E0_N, cursor0, col0);

  gemm0_kernel<<<dim3((N_SRC + 127) / 128), 512, 0, stream>>>(x, wt0, waG, h0, as0, ad0);

  agg0_kernel<<<dim3(N_DST0 / 4), 256, 0, stream>>>(h0, as0, ad0, row_ptr0, col0, bias0, out0);

  bn_stats<<<dim3((N_DST0 + 127) / 128), 256, 0, stream>>>(out0, gsum, gsq);
  bn_final<<<1, 256, 0, stream>>>(gsum, gsq, gamma0, beta0, scaleb, shiftb);

  // CSR graph 1
  hist_kernel<<<dim3(E1_N / 256), 256, 0, stream>>>(edst1, E1_N, cnt1);
  scanA<<<dim3(40), 256, 0, stream>>>(cnt1, N_DST1, partials);
  scanB<<<1, 256, 0, stream>>>(partials, 40);
  scanC<<<dim3(40), 256, 0, stream>>>(cnt1, N_DST1, partials, row_ptr1, cursor1);
  scatter_kernel<<<dim3(E1_N / 256), 256, 0, stream>>>(esrc1, edst1, E1_N, cursor1, col1);

  gemm1_kernel<<<dim3((N_DST0 + 255) / 256), 256, 0, stream>>>(out0, w1t, wa1G, scaleb, shiftb,
                                                               h1, as1, ad1);

  agg1_kernel<<<dim3(N_DST1 / 4), 256, 0, stream>>>(h1, as1, ad1, row_ptr1, col1, bias1, out);
}

// Round 4
// 363.381 us; speedup vs baseline: 1.3021x; 1.0475x over previous
//
#include <hip/hip_runtime.h>
#include <stdint.h>

#define N_SRC  200000
#define N_DST0 50000
#define N_DST1 10000
#define E0_N   800000
#define E1_N   320000
#define E_TOT  (E0_N + E1_N)
#define NSEG   (N_DST0 + N_DST1)
#define IN_C   128
#define HID    64
#define H0_N   4
#define C0     256      // H0*HID
#define OUTC   40
#define H1W    48       // padded h1 width
#define NEG_SLOPE 0.2f
#define BN_EPS 1e-5f

typedef __attribute__((ext_vector_type(8))) short short8;
typedef __attribute__((ext_vector_type(4))) float f32x4;
typedef __attribute__((ext_vector_type(4))) unsigned short u16x4;

__device__ __forceinline__ float bf2f(unsigned short u){
  union{unsigned int i; float f;} v; v.i = ((unsigned int)u) << 16; return v.f;
}
__device__ __forceinline__ unsigned short f2bf(float f){   // RNE (weights only)
  union{float f; unsigned int i;} v; v.f = f;
  unsigned int u = v.i;
  unsigned int r = (u + 0x7FFFu + ((u >> 16) & 1u)) >> 16;
  return (unsigned short)r;
}
// truncate-pack two f32 -> one u32 of 2 bf16
__device__ __forceinline__ unsigned int pkt(float a, float b){
  return (__float_as_uint(a) >> 16) | (__float_as_uint(b) & 0xFFFF0000u);
}
__device__ __forceinline__ unsigned short tbf(float f){
  return (unsigned short)(__float_as_uint(f) >> 16);
}
__device__ __forceinline__ float lrelu(float x){ return x > 0.f ? x : NEG_SLOPE * x; }

// ---------------- prep: all weight transforms in one kernel ----------------
__global__ void prep_all(const float* __restrict__ W0, const float* __restrict__ W1,
                         const float* __restrict__ as0a, const float* __restrict__ ad0a,
                         const float* __restrict__ as1a, const float* __restrict__ ad1a,
                         unsigned short* __restrict__ wt0, unsigned short* __restrict__ w1t,
                         unsigned short* __restrict__ waG, unsigned short* __restrict__ wa1G)
{
  int b = blockIdx.x, t = threadIdx.x;
  if (b < 128){                       // wt0: 256x128
    int idx = b * 256 + t;
    int n = idx / IN_C, k = idx % IN_C;
    wt0[idx] = f2bf(W0[k * C0 + n]);
  } else if (b < 176){                // w1t: 48x256
    int idx = (b - 128) * 256 + t;
    int n = idx / C0, k = idx % C0;
    w1t[idx] = (n < OUTC) ? f2bf(W1[k * OUTC + n]) : (unsigned short)0;
  } else {                            // waG 8x128, wa1G 2x256
    int idx = (b - 176) * 256 + t;
    if (idx < 1024){
      int k = idx >> 3, j = idx & 7, h = j & 3;
      const float* att = (j < 4) ? as0a : ad0a;
      float s = 0.f;
      #pragma unroll
      for (int c = 0; c < HID; c++) s += W0[k * C0 + h * HID + c] * att[h * HID + c];
      waG[j * IN_C + k] = f2bf(s);
    } else if (idx < 1536){
      int r = idx - 1024; int k = r >> 1, j = r & 1;
      const float* att = j ? ad1a : as1a;
      float s = 0.f;
      #pragma unroll
      for (int c = 0; c < OUTC; c++) s += W1[k * OUTC + c] * att[c];
      wa1G[j * C0 + k] = f2bf(s);
    }
  }
}

// ---------------- GEMM0: h0 = x @ W0 (bf16) + alpha via WA-MFMA ----------------
// block 256 (4 waves), grid-stride over 3125 64-row tiles. B-frags in registers,
// A double-buffered in LDS, async prefetch of next tile during MFMA.
__global__ __launch_bounds__(256) void gemm0_kernel(
    const float* __restrict__ x, const unsigned short* __restrict__ wt0,
    const unsigned short* __restrict__ waG,
    unsigned short* __restrict__ h0, float* __restrict__ as0, float* __restrict__ ad0)
{
  __shared__ __align__(16) unsigned short aT[2][64 * 136];
  int tid = threadIdx.x;
  int w = tid >> 6, lane = tid & 63, lo = lane & 15, hi = lane >> 4;

  // B fragments: wave w owns head w (cols w*64 .. w*64+63); from global (L2-hot)
  short8 B[4][4];
  #pragma unroll
  for (int nf = 0; nf < 4; nf++)
    #pragma unroll
    for (int kf = 0; kf < 4; kf++)
      B[nf][kf] = *(const short8*)&wt0[(w * 64 + nf * 16 + lo) * IN_C + kf * 32 + hi * 8];
  // alpha B-frags on wave 0 (rows 0..7 = [as h0..3 | ad h0..3], rows 8..15 zero)
  short8 WA[4];
  {
    short8 z8 = {0,0,0,0,0,0,0,0};
    #pragma unroll
    for (int kf = 0; kf < 4; kf++)
      WA[kf] = (w == 0 && lo < 8) ? *(const short8*)&waG[lo * IN_C + kf * 32 + hi * 8] : z8;
  }

  const int nt = N_SRC / 64;   // 3125 exactly
  int rt = blockIdx.x;
  if (rt >= nt) return;
  f32x4 pf[8];
  #pragma unroll
  for (int i = 0; i < 8; i++){
    int fi = tid + i * 256, row = fi >> 5, q = fi & 31;
    pf[i] = ((const f32x4*)x)[(size_t)(rt * 64 + row) * 32 + q];
  }
  int parity = 0;
  for (;;){
    // write staged tile (f32 regs -> bf16 LDS)
    #pragma unroll
    for (int i = 0; i < 8; i++){
      int fi = tid + i * 256, row = fi >> 5, q = fi & 31;
      uint2 pk; pk.x = pkt(pf[i][0], pf[i][1]); pk.y = pkt(pf[i][2], pf[i][3]);
      *(uint2*)&aT[parity][row * 136 + q * 4] = pk;
    }
    __syncthreads();
    int rt_next = rt + gridDim.x;
    bool more = rt_next < nt;
    if (more){
      #pragma unroll
      for (int i = 0; i < 8; i++){
        int fi = tid + i * 256, row = fi >> 5, q = fi & 31;
        pf[i] = ((const f32x4*)x)[(size_t)(rt_next * 64 + row) * 32 + q];
      }
    }
    // compute
    f32x4 zero4 = {0.f, 0.f, 0.f, 0.f};
    f32x4 acc[4][4], acc_a[4];
    #pragma unroll
    for (int mf = 0; mf < 4; mf++){
      acc_a[mf] = zero4;
      #pragma unroll
      for (int nf = 0; nf < 4; nf++) acc[mf][nf] = zero4;
    }
    #pragma unroll
    for (int kf = 0; kf < 4; kf++){
      int kb = kf * 32 + hi * 8;
      short8 a[4];
      #pragma unroll
      for (int mf = 0; mf < 4; mf++) a[mf] = *(const short8*)&aT[parity][(mf * 16 + lo) * 136 + kb];
      #pragma unroll
      for (int mf = 0; mf < 4; mf++)
        #pragma unroll
        for (int nf = 0; nf < 4; nf++)
          acc[mf][nf] = __builtin_amdgcn_mfma_f32_16x16x32_bf16(a[mf], B[nf][kf], acc[mf][nf], 0, 0, 0);
      if (w == 0){
        #pragma unroll
        for (int mf = 0; mf < 4; mf++)
          acc_a[mf] = __builtin_amdgcn_mfma_f32_16x16x32_bf16(a[mf], WA[kf], acc_a[mf], 0, 0, 0);
      }
    }
    // stores
    int r0 = rt * 64;
    #pragma unroll
    for (int mf = 0; mf < 4; mf++)
      #pragma unroll
      for (int rg = 0; rg < 4; rg++){
        int row = r0 + mf * 16 + hi * 4 + rg;
        #pragma unroll
        for (int nf = 0; nf < 4; nf++)
          h0[(size_t)row * C0 + w * 64 + nf * 16 + lo] = tbf(acc[mf][nf][rg]);
      }
    if (w == 0 && lo < 8){
      #pragma unroll
      for (int mf = 0; mf < 4; mf++)
        #pragma unroll
        for (int rg = 0; rg < 4; rg++){
          int row = r0 + mf * 16 + hi * 4 + rg;
          float v = acc_a[mf][rg];
          if (lo < 4) as0[row * H0_N + lo] = v;
          else if (row < N_DST0) ad0[row * H0_N + (lo - 4)] = v;
        }
    }
    if (!more) break;
    rt = rt_next; parity ^= 1;
  }
}

// ---------------- CSR build (both graphs concatenated: segs 0..49999 = g0, 50000..59999 = g1) ----------------
__global__ void hist_kernel(const int* __restrict__ edst0, const int* __restrict__ edst1,
                            int* __restrict__ cnt){
  int e = blockIdx.x * 256 + threadIdx.x;
  if (e < E0_N) atomicAdd(&cnt[edst0[e]], 1);
  else if (e < E_TOT) atomicAdd(&cnt[N_DST0 + edst1[e - E0_N]], 1);
}
__global__ void scanA(const int* __restrict__ cnt, int* __restrict__ partials){
  __shared__ int s[256];
  int i = blockIdx.x * 256 + threadIdx.x;
  s[threadIdx.x] = (i < NSEG) ? cnt[i] : 0;
  __syncthreads();
  for (int off = 128; off > 0; off >>= 1){
    if (threadIdx.x < off) s[threadIdx.x] += s[threadIdx.x + off];
    __syncthreads();
  }
  if (threadIdx.x == 0) partials[blockIdx.x] = s[0];
}
__global__ void scanB(int* __restrict__ partials, int nb){
  __shared__ int s[256];
  int t = threadIdx.x;
  int v = (t < nb) ? partials[t] : 0;
  s[t] = v; __syncthreads();
  for (int off = 1; off < 256; off <<= 1){
    int u = (t >= off) ? s[t - off] : 0;
    __syncthreads();
    s[t] += u;
    __syncthreads();
  }
  if (t < nb) partials[t] = s[t] - v;     // exclusive
}
__global__ void scanC(const int* __restrict__ cnt, const int* __restrict__ partials,
                      int* __restrict__ row_ptr, int* __restrict__ cursor){
  __shared__ int s[256];
  int t = threadIdx.x; int i = blockIdx.x * 256 + t;
  int v = (i < NSEG) ? cnt[i] : 0;
  s[t] = v; __syncthreads();
  for (int off = 1; off < 256; off <<= 1){
    int u = (t >= off) ? s[t - off] : 0;
    __syncthreads();
    s[t] += u;
    __syncthreads();
  }
  int excl = s[t] - v + partials[blockIdx.x];
  if (i < NSEG){
    row_ptr[i] = excl; cursor[i] = excl;
    if (i == NSEG - 1) row_ptr[NSEG] = excl + v;
  }
}
__global__ void scatter_kernel(const int* __restrict__ esrc0, const int* __restrict__ edst0,
                               const int* __restrict__ esrc1, const int* __restrict__ edst1,
                               int* __restrict__ cursor, int* __restrict__ col){
  int e = blockIdx.x * 256 + threadIdx.x;
  if (e < E0_N){
    int pos = atomicAdd(&cursor[edst0[e]], 1);
    col[pos] = esrc0[e];
  } else if (e < E_TOT){
    int i = e - E0_N;
    int pos = atomicAdd(&cursor[N_DST0 + edst1[i]], 1);
    col[pos] = esrc1[i];
  }
}

// ---------------- agg0: max pass + chunked LDS alphas + gather ----------------
__global__ __launch_bounds__(256) void agg0_kernel(
    const unsigned short* __restrict__ h0, const float* __restrict__ as0, const float* __restrict__ ad0,
    const int* __restrict__ row_ptr, const int* __restrict__ col,
    const float* __restrict__ bias0, unsigned short* __restrict__ out0)
{
  __shared__ f32x4 sp[4][64];
  __shared__ int   sc[4][64];
  int gid = blockIdx.x * 256 + threadIdx.x;
  int w = threadIdx.x >> 6;
  int d = gid >> 6, t = gid & 63;
  if (d >= N_DST0) return;
  int rs = row_ptr[d], re = row_ptr[d + 1];
  f32x4 adv = ((const f32x4*)ad0)[d];
  f32x4 asd = ((const f32x4*)as0)[d];
  f32x4 es;
  #pragma unroll
  for (int h = 0; h < 4; h++) es[h] = lrelu(asd[h] + adv[h]);

  // phase 1: max only
  f32x4 m4 = {-1e30f, -1e30f, -1e30f, -1e30f};
  for (int i = rs + t; i < re; i += 64){
    int s = col[i];
    f32x4 a4 = ((const f32x4*)as0)[s];
    #pragma unroll
    for (int h = 0; h < 4; h++) m4[h] = fmaxf(m4[h], lrelu(a4[h] + adv[h]));
  }
  #pragma unroll
  for (int msk = 1; msk < 64; msk <<= 1){
    #pragma unroll
    for (int h = 0; h < 4; h++) m4[h] = fmaxf(m4[h], __shfl_xor(m4[h], msk));
  }
  #pragma unroll
  for (int h = 0; h < 4; h++) m4[h] = fmaxf(m4[h], es[h]);

  int ht = t >> 4;
  float acc0 = 0.f, acc1 = 0.f, acc2 = 0.f, acc3 = 0.f;
  f32x4 zl = {0.f, 0.f, 0.f, 0.f};
  const float* spf = (const float*)sp;

  for (int c = rs; c < re; c += 64){
    int i = c + t;
    if (i < re){
      int s = col[i];
      f32x4 a4 = ((const f32x4*)as0)[s];
      f32x4 q4;
      #pragma unroll
      for (int h = 0; h < 4; h++){
        q4[h] = __expf(lrelu(a4[h] + adv[h]) - m4[h]);
        zl[h] += q4[h];
      }
      sp[w][t] = q4; sc[w][t] = s;
    }
    asm volatile("s_waitcnt lgkmcnt(0)" ::: "memory");
    int n = re - c; if (n > 64) n = 64;
    for (int j = 0; j < n; j++){
      int s = sc[w][j];
      float p = spf[(w * 64 + j) * 4 + ht];
      u16x4 hv = *(const u16x4*)&h0[(size_t)s * C0 + t * 4];
      acc0 += bf2f(hv[0]) * p; acc1 += bf2f(hv[1]) * p;
      acc2 += bf2f(hv[2]) * p; acc3 += bf2f(hv[3]) * p;
    }
    asm volatile("s_waitcnt lgkmcnt(0)" ::: "memory");
  }
  // z reduce + self loop
  #pragma unroll
  for (int msk = 1; msk < 64; msk <<= 1){
    #pragma unroll
    for (int h = 0; h < 4; h++) zl[h] += __shfl_xor(zl[h], msk);
  }
  #pragma unroll
  for (int h = 0; h < 4; h++) zl[h] += __expf(es[h] - m4[h]);
  float qs = __expf(es[ht] - m4[ht]);
  {
    u16x4 hv = *(const u16x4*)&h0[(size_t)d * C0 + t * 4];
    acc0 += bf2f(hv[0]) * qs; acc1 += bf2f(hv[1]) * qs;
    acc2 += bf2f(hv[2]) * qs; acc3 += bf2f(hv[3]) * qs;
  }
  float rz = 1.f / zl[ht];
  f32x4 b4 = ((const f32x4*)bias0)[t];
  uint2 pk;
  pk.x = pkt(acc0 * rz + b4[0], acc1 * rz + b4[1]);
  pk.y = pkt(acc2 * rz + b4[2], acc3 * rz + b4[3]);
  ((uint2*)out0)[(size_t)d * 64 + t] = pk;
}

// ---------------- BatchNorm stats (bf16 input) ----------------
__global__ void bn_stats(const unsigned short* __restrict__ out0, float* __restrict__ gsum, float* __restrict__ gsq){
  int t = threadIdx.x;
  int r0 = blockIdx.x * 128;
  int rend = r0 + 128; if (rend > N_DST0) rend = N_DST0;
  float s = 0.f, q = 0.f;
  for (int r = r0; r < rend; r++){
    float v = bf2f(out0[(size_t)r * C0 + t]);
    s += v; q += v * v;
  }
  atomicAdd(&gsum[t], s);
  atomicAdd(&gsq[t], q);
}

// ---------------- GEMM1: h1 = relu(bn(out0)) @ W1 + alpha; bn_final folded in ----------------
// block 256 (4 waves), tile 128 rows x 48 cols, K chunks of 64. grid 391.
__global__ __launch_bounds__(256) void gemm1_kernel(
    const unsigned short* __restrict__ out0, const unsigned short* __restrict__ w1t,
    const unsigned short* __restrict__ wa1G,
    const float* __restrict__ gsum, const float* __restrict__ gsq,
    const float* __restrict__ gamma, const float* __restrict__ beta,
    float* __restrict__ h1, float* __restrict__ as1, float* __restrict__ ad1)
{
  __shared__ __align__(16) unsigned short aT[128 * 72];
  __shared__ __align__(16) unsigned short wT[48 * 72];
  __shared__ __align__(16) unsigned short wa1T[16 * 72];
  __shared__ float scL[C0], shL[C0];
  int tid = threadIdx.x;
  int r0 = blockIdx.x * 128;
  int w = tid >> 6, lane = tid & 63, lo = lane & 15, hi = lane >> 4;

  {
    float mu = gsum[tid] * (1.f / N_DST0);
    float var = gsq[tid] * (1.f / N_DST0) - mu * mu;
    float rs = rsqrtf(var + BN_EPS);
    float sc = gamma[tid] * rs;
    scL[tid] = sc;
    shL[tid] = beta[tid] - mu * sc;
  }
  __syncthreads();

  f32x4 zero4 = {0.f, 0.f, 0.f, 0.f};
  f32x4 acc[2][3], acc_a[2];
  #pragma unroll
  for (int mf = 0; mf < 2; mf++){
    acc_a[mf] = zero4;
    #pragma unroll
    for (int nf = 0; nf < 3; nf++) acc[mf][nf] = zero4;
  }

  for (int kc = 0; kc < 4; kc++){
    if (kc) __syncthreads();
    // stage A chunk: 128 rows x 64 k (BN+ReLU applied)
    #pragma unroll
    for (int i = 0; i < 8; i++){
      int fi = tid + i * 256;          // 0..2047
      int row = fi >> 4, kq = fi & 15;
      int r = r0 + row;
      u16x4 v = {0,0,0,0};
      if (r < N_DST0) v = ((const u16x4*)out0)[(size_t)r * 64 + kc * 16 + kq];
      f32x4 sc4 = ((const f32x4*)scL)[kc * 16 + kq];
      f32x4 sh4 = ((const f32x4*)shL)[kc * 16 + kq];
      float f[4];
      #pragma unroll
      for (int j = 0; j < 4; j++){
        float u = bf2f(v[j]) * sc4[j] + sh4[j];
        f[j] = u > 0.f ? u : 0.f;
      }
      uint2 pk; pk.x = pkt(f[0], f[1]); pk.y = pkt(f[2], f[3]);
      *(uint2*)&aT[row * 72 + kq * 4] = pk;
    }
    // stage W chunk: 48 x 64
    #pragma unroll
    for (int i = 0; i < 3; i++){
      int fi = tid + i * 256;          // 0..767
      int n = fi >> 4, kq = fi & 15;
      *(u16x4*)&wT[n * 72 + kq * 4] = ((const u16x4*)w1t)[n * 64 + kc * 16 + kq];
    }
    // stage WA1 chunk: rows 0..1 data, rest zero
    {
      int n = tid >> 4, kq = tid & 15;
      u16x4 v = {0,0,0,0};
      if (n < 2) v = ((const u16x4*)wa1G)[n * 64 + kc * 16 + kq];
      *(u16x4*)&wa1T[n * 72 + kq * 4] = v;
    }
    __syncthreads();
    #pragma unroll
    for (int kk = 0; kk < 2; kk++){
      int kb = kk * 32 + hi * 8;
      short8 a[2], b[3];
      #pragma unroll
      for (int mf = 0; mf < 2; mf++) a[mf] = *(const short8*)&aT[(w * 32 + mf * 16 + lo) * 72 + kb];
      #pragma unroll
      for (int nf = 0; nf < 3; nf++) b[nf] = *(const short8*)&wT[(nf * 16 + lo) * 72 + kb];
      short8 wab = *(const short8*)&wa1T[lo * 72 + kb];
      #pragma unroll
      for (int mf = 0; mf < 2; mf++){
        #pragma unroll
        for (int nf = 0; nf < 3; nf++)
          acc[mf][nf] = __builtin_amdgcn_mfma_f32_16x16x32_bf16(a[mf], b[nf], acc[mf][nf], 0, 0, 0);
        acc_a[mf] = __builtin_amdgcn_mfma_f32_16x16x32_bf16(a[mf], wab, acc_a[mf], 0, 0, 0);
      }
    }
  }

  // epilogue
  #pragma unroll
  for (int mf = 0; mf < 2; mf++)
    #pragma unroll
    for (int rg = 0; rg < 4; rg++){
      int r = r0 + w * 32 + mf * 16 + hi * 4 + rg;
      if (r < N_DST0){
        #pragma unroll
        for (int nf = 0; nf < 3; nf++)
          h1[(size_t)r * H1W + nf * 16 + lo] = acc[mf][nf][rg];
        if (lo == 0) as1[r] = acc_a[mf][rg];
        else if (lo == 1 && r < N_DST1) ad1[r] = acc_a[mf][rg];
      }
    }
}

// ---------------- agg1: max pass + chunked LDS alphas + gather + log_softmax ----------------
__global__ __launch_bounds__(256) void agg1_kernel(
    const float* __restrict__ h1, const float* __restrict__ as1, const float* __restrict__ ad1,
    const int* __restrict__ row_ptr, const int* __restrict__ col,
    const float* __restrict__ bias1, float* __restrict__ out)
{
  __shared__ float sp1[4][64];
  __shared__ int   sc1[4][64];
  int gid = blockIdx.x * 256 + threadIdx.x;
  int w = threadIdx.x >> 6;
  int d = gid >> 6, t = gid & 63;
  if (d >= N_DST1) return;
  int rs = row_ptr[N_DST0 + d], re = row_ptr[N_DST0 + d + 1];
  float adv = ad1[d];
  float es = lrelu(as1[d] + adv);
  float m = -1e30f;
  for (int i = rs + t; i < re; i += 64) m = fmaxf(m, lrelu(as1[col[i]] + adv));
  #pragma unroll
  for (int msk = 1; msk < 64; msk <<= 1) m = fmaxf(m, __shfl_xor(m, msk));
  m = fmaxf(m, es);

  bool tl = (t < H1W);
  float zl = 0.f, acc = 0.f;
  for (int c = rs; c < re; c += 64){
    int i = c + t;
    if (i < re){
      int s = col[i];
      float q = __expf(lrelu(as1[s] + adv) - m);
      zl += q;
      sp1[w][t] = q; sc1[w][t] = s;
    }
    asm volatile("s_waitcnt lgkmcnt(0)" ::: "memory");
    int n = re - c; if (n > 64) n = 64;
    for (int j = 0; j < n; j++){
      int s = sc1[w][j];
      float p = sp1[w][j];
      float hv = tl ? h1[(size_t)s * H1W + t] : 0.f;
      acc += p * hv;
    }
    asm volatile("s_waitcnt lgkmcnt(0)" ::: "memory");
  }
  #pragma unroll
  for (int msk = 1; msk < 64; msk <<= 1) zl += __shfl_xor(zl, msk);
  float qs = __expf(es - m);
  float z = zl + qs;
  float hs = tl ? h1[(size_t)d * H1W + t] : 0.f;
  acc = (acc + qs * hs) / z;
  float v = acc + ((t < OUTC) ? bias1[t] : 0.f);
  float vm = (t < OUTC) ? v : -1e30f;
  #pragma unroll
  for (int msk = 1; msk < 64; msk <<= 1) vm = fmaxf(vm, __shfl_xor(vm, msk));
  float ex = (t < OUTC) ? __expf(v - vm) : 0.f;
  #pragma unroll
  for (int msk = 1; msk < 64; msk <<= 1) ex += __shfl_xor(ex, msk);
  if (t < OUTC) out[(size_t)d * OUTC + t] = v - vm - __logf(ex);
}

// ---------------- launch ----------------
extern "C" void kernel_launch(void* const* d_in, const int* in_sizes, int n_in,
                              void* d_out, int out_size, void* d_ws, size_t ws_size,
                              hipStream_t stream)
{
  const float* x        = (const float*)d_in[0];
  const float* W0       = (const float*)d_in[1];
  const float* att_src0 = (const float*)d_in[2];
  const float* att_dst0 = (const float*)d_in[3];
  const float* bias0    = (const float*)d_in[4];
  const float* gamma0   = (const float*)d_in[5];
  const float* beta0    = (const float*)d_in[6];
  const float* W1       = (const float*)d_in[7];
  const float* att_src1 = (const float*)d_in[8];
  const float* att_dst1 = (const float*)d_in[9];
  const float* bias1    = (const float*)d_in[10];
  const int* esrc0 = (const int*)d_in[11];
  const int* edst0 = (const int*)d_in[12];
  const int* esrc1 = (const int*)d_in[13];
  const int* edst1 = (const int*)d_in[14];
  float* out = (float*)d_out;

  char* p = (char*)d_ws;
  auto alloc = [&](size_t b) -> char* {
    char* r = p; p += (b + 255) & ~(size_t)255; return r;
  };
  unsigned short* h0   = (unsigned short*)alloc((size_t)N_SRC * C0 * 2);    // 102.4 MB
  unsigned short* out0 = (unsigned short*)alloc((size_t)N_DST0 * C0 * 2);   // 25.6 MB
  unsigned short* wt0  = (unsigned short*)alloc((size_t)C0 * IN_C * 2);
  unsigned short* w1t  = (unsigned short*)alloc((size_t)H1W * C0 * 2);
  unsigned short* waG  = (unsigned short*)alloc((size_t)8 * IN_C * 2);
  unsigned short* wa1G = (unsigned short*)alloc((size_t)2 * C0 * 2);
  float* as0          = (float*)alloc((size_t)N_SRC * H0_N * 4);
  float* ad0          = (float*)alloc((size_t)N_DST0 * H0_N * 4);
  float* h1           = (float*)alloc((size_t)N_DST0 * H1W * 4);
  float* as1          = (float*)alloc((size_t)N_DST0 * 4);
  float* ad1          = (float*)alloc((size_t)N_DST1 * 4);
  int* row_ptr        = (int*)alloc((size_t)(NSEG + 1) * 4);
  int* cursor         = (int*)alloc((size_t)NSEG * 4);
  int* col            = (int*)alloc((size_t)E_TOT * 4);
  int* partials       = (int*)alloc((size_t)256 * 4);
  // contiguous zero zone
  char* zbase = p;
  int* cnt    = (int*)alloc((size_t)NSEG * 4);
  float* gsum = (float*)alloc((size_t)C0 * 4);
  float* gsq  = (float*)alloc((size_t)C0 * 4);
  size_t zspan = (size_t)(p - zbase);
  hipMemsetAsync(zbase, 0, zspan, stream);

  prep_all<<<dim3(182), 256, 0, stream>>>(W0, W1, att_src0, att_dst0, att_src1, att_dst1,
                                          wt0, w1t, waG, wa1G);

  // combined CSR build (before gemm0 so h0 stays hot in L3 for agg0)
  hist_kernel<<<dim3(E_TOT / 256), 256, 0, stream>>>(edst0, edst1, cnt);
  scanA<<<dim3((NSEG + 255) / 256), 256, 0, stream>>>(cnt, partials);
  scanB<<<1, 256, 0, stream>>>(partials, (NSEG + 255) / 256);
  scanC<<<dim3((NSEG + 255) / 256), 256, 0, stream>>>(cnt, partials, row_ptr, cursor);
  scatter_kernel<<<dim3(E_TOT / 256), 256, 0, stream>>>(esrc0, edst0, esrc1, edst1, cursor, col);

  gemm0_kernel<<<dim3(1042), 256, 0, stream>>>(x, wt0, waG, h0, as0, ad0);

  agg0_kernel<<<dim3(N_DST0 / 4), 256, 0, stream>>>(h0, as0, ad0, row_ptr, col, bias0, out0);

  bn_stats<<<dim3((N_DST0 + 127) / 128), 256, 0, stream>>>(out0, gsum, gsq);

  gemm1_kernel<<<dim3((N_DST0 + 127) / 128), 256, 0, stream>>>(out0, w1t, wa1G,
                                                               gsum, gsq, gamma0, beta0,
                                                               h1, as1, ad1);

  agg1_kernel<<<dim3(N_DST1 / 4), 256, 0, stream>>>(h1, as1, ad1, row_ptr, col, bias1, out);
}

// Round 5
// 308.310 us; speedup vs baseline: 1.5347x; 1.1786x over previous
//
#include <hip/hip_runtime.h>
#include <stdint.h>

#define N_SRC  200000
#define N_DST0 50000
#define N_DST1 10000
#define E0_N   800000
#define E1_N   320000
#define E_TOT  (E0_N + E1_N)
#define NSEG   (N_DST0 + N_DST1)
#define IN_C   128
#define HID    64
#define H0_N   4
#define C0     256      // H0*HID
#define OUTC   40
#define H1W    48       // padded h1 width
#define NEG_SLOPE 0.2f
#define BN_EPS 1e-5f

#define NB_PREP 182
#define NB_HIST (E_TOT / 256)        // 4375
#define NB_GEMM (N_SRC / 64)         // 3125
#define NB_SCAT (E_TOT / 256)        // 4375  (3125:4375 = 5:7, 7500 = 12*625)

typedef __attribute__((ext_vector_type(8))) short short8;
typedef __attribute__((ext_vector_type(4))) float f32x4;
typedef __attribute__((ext_vector_type(4))) unsigned short u16x4;

__device__ __forceinline__ float bf2f(unsigned short u){
  union{unsigned int i; float f;} v; v.i = ((unsigned int)u) << 16; return v.f;
}
__device__ __forceinline__ unsigned short f2bf(float f){   // RNE (weights only)
  union{float f; unsigned int i;} v; v.f = f;
  unsigned int u = v.i;
  unsigned int r = (u + 0x7FFFu + ((u >> 16) & 1u)) >> 16;
  return (unsigned short)r;
}
// truncate-pack two f32 -> one u32 of 2 bf16
__device__ __forceinline__ unsigned int pkt(float a, float b){
  return (__float_as_uint(a) >> 16) | (__float_as_uint(b) & 0xFFFF0000u);
}
__device__ __forceinline__ unsigned short tbf(float f){
  return (unsigned short)(__float_as_uint(f) >> 16);
}
__device__ __forceinline__ float lrelu(float x){ return x > 0.f ? x : NEG_SLOPE * x; }

// ---------------- K1: prep (blocks 0..181) || hist (blocks 182..) ----------------
__global__ void prep_hist_kernel(const float* __restrict__ W0, const float* __restrict__ W1,
                                 const float* __restrict__ as0a, const float* __restrict__ ad0a,
                                 const float* __restrict__ as1a, const float* __restrict__ ad1a,
                                 unsigned short* __restrict__ wt0, unsigned short* __restrict__ w1t,
                                 unsigned short* __restrict__ waG, unsigned short* __restrict__ wa1G,
                                 const int* __restrict__ edst0, const int* __restrict__ edst1,
                                 int* __restrict__ cnt)
{
  int b = blockIdx.x, t = threadIdx.x;
  if (b >= NB_PREP){
    int e = (b - NB_PREP) * 256 + t;
    if (e < E0_N) atomicAdd(&cnt[edst0[e]], 1);
    else if (e < E_TOT) atomicAdd(&cnt[N_DST0 + edst1[e - E0_N]], 1);
    return;
  }
  if (b < 128){                       // wt0: 256x128
    int idx = b * 256 + t;
    int n = idx / IN_C, k = idx % IN_C;
    wt0[idx] = f2bf(W0[k * C0 + n]);
  } else if (b < 176){                // w1t: 48x256
    int idx = (b - 128) * 256 + t;
    int n = idx / C0, k = idx % C0;
    w1t[idx] = (n < OUTC) ? f2bf(W1[k * OUTC + n]) : (unsigned short)0;
  } else {                            // waG 8x128, wa1G 2x256
    int idx = (b - 176) * 256 + t;
    if (idx < 1024){
      int k = idx >> 3, j = idx & 7, h = j & 3;
      const float* att = (j < 4) ? as0a : ad0a;
      float s = 0.f;
      #pragma unroll
      for (int c = 0; c < HID; c++) s += W0[k * C0 + h * HID + c] * att[h * HID + c];
      waG[j * IN_C + k] = f2bf(s);
    } else if (idx < 1536){
      int r = idx - 1024; int k = r >> 1, j = r & 1;
      const float* att = j ? ad1a : as1a;
      float s = 0.f;
      #pragma unroll
      for (int c = 0; c < OUTC; c++) s += W1[k * OUTC + c] * att[c];
      wa1G[j * C0 + k] = f2bf(s);
    }
  }
}

// ---------------- scans ----------------
__global__ void scanA(const int* __restrict__ cnt, int* __restrict__ partials){
  __shared__ int s[256];
  int i = blockIdx.x * 256 + threadIdx.x;
  s[threadIdx.x] = (i < NSEG) ? cnt[i] : 0;
  __syncthreads();
  for (int off = 128; off > 0; off >>= 1){
    if (threadIdx.x < off) s[threadIdx.x] += s[threadIdx.x + off];
    __syncthreads();
  }
  if (threadIdx.x == 0) partials[blockIdx.x] = s[0];
}
__global__ void scanB(int* __restrict__ partials, int nb){
  __shared__ int s[256];
  int t = threadIdx.x;
  int v = (t < nb) ? partials[t] : 0;
  s[t] = v; __syncthreads();
  for (int off = 1; off < 256; off <<= 1){
    int u = (t >= off) ? s[t - off] : 0;
    __syncthreads();
    s[t] += u;
    __syncthreads();
  }
  if (t < nb) partials[t] = s[t] - v;     // exclusive
}
__global__ void scanC(const int* __restrict__ cnt, const int* __restrict__ partials,
                      int* __restrict__ row_ptr, int* __restrict__ cursor){
  __shared__ int s[256];
  int t = threadIdx.x; int i = blockIdx.x * 256 + t;
  int v = (i < NSEG) ? cnt[i] : 0;
  s[t] = v; __syncthreads();
  for (int off = 1; off < 256; off <<= 1){
    int u = (t >= off) ? s[t - off] : 0;
    __syncthreads();
    s[t] += u;
    __syncthreads();
  }
  int excl = s[t] - v + partials[blockIdx.x];
  if (i < NSEG){
    row_ptr[i] = excl; cursor[i] = excl;
    if (i == NSEG - 1) row_ptr[NSEG] = excl + v;
  }
}

// ---------------- K2: gemm0 (5/12 of blocks) || scatter (7/12) ----------------
// gemm0: h0 = x @ W0 (bf16) + alpha via WA-MFMA; one 64-row tile per block,
// B-frags in registers (L2-hot), single-buffer LDS for A.
// scatter: CSR column fill via cursor atomics.
__global__ __launch_bounds__(256) void gemm0_scatter_kernel(
    const float* __restrict__ x, const unsigned short* __restrict__ wt0,
    const unsigned short* __restrict__ waG,
    unsigned short* __restrict__ h0, float* __restrict__ as0, float* __restrict__ ad0,
    const int* __restrict__ esrc0, const int* __restrict__ edst0,
    const int* __restrict__ esrc1, const int* __restrict__ edst1,
    int* __restrict__ cursor, int* __restrict__ col)
{
  __shared__ __align__(16) unsigned short aT[64 * 136];
  int b = blockIdx.x;
  int r12 = b % 12, q12 = b / 12;
  int tid = threadIdx.x;

  if (r12 >= 5){
    // ---- scatter role ----
    int sb = q12 * 7 + (r12 - 5);
    int e = sb * 256 + tid;
    if (e < E0_N){
      int pos = atomicAdd(&cursor[edst0[e]], 1);
      col[pos] = esrc0[e];
    } else if (e < E_TOT){
      int i = e - E0_N;
      int pos = atomicAdd(&cursor[N_DST0 + edst1[i]], 1);
      col[pos] = esrc1[i];
    }
    return;
  }
  // ---- gemm role ----
  int g = q12 * 5 + r12;              // 0..3124
  int w = tid >> 6, lane = tid & 63, lo = lane & 15, hi = lane >> 4;
  int r0 = g * 64;

  // x tile into regs (issue first, deepest latency)
  f32x4 pf[8];
  #pragma unroll
  for (int i = 0; i < 8; i++){
    int fi = tid + i * 256, row = fi >> 5, q = fi & 31;
    pf[i] = ((const f32x4*)x)[(size_t)(r0 + row) * 32 + q];
  }
  // B fragments: wave w owns head w (cols w*64 .. w*64+63)
  short8 B[4][4];
  #pragma unroll
  for (int nf = 0; nf < 4; nf++)
    #pragma unroll
    for (int kf = 0; kf < 4; kf++)
      B[nf][kf] = *(const short8*)&wt0[(w * 64 + nf * 16 + lo) * IN_C + kf * 32 + hi * 8];
  short8 WA[4];
  {
    short8 z8 = {0,0,0,0,0,0,0,0};
    #pragma unroll
    for (int kf = 0; kf < 4; kf++)
      WA[kf] = (w == 0 && lo < 8) ? *(const short8*)&waG[lo * IN_C + kf * 32 + hi * 8] : z8;
  }
  // stage A (f32 regs -> bf16 LDS)
  #pragma unroll
  for (int i = 0; i < 8; i++){
    int fi = tid + i * 256, row = fi >> 5, q = fi & 31;
    uint2 pk; pk.x = pkt(pf[i][0], pf[i][1]); pk.y = pkt(pf[i][2], pf[i][3]);
    *(uint2*)&aT[row * 136 + q * 4] = pk;
  }
  __syncthreads();

  f32x4 zero4 = {0.f, 0.f, 0.f, 0.f};
  f32x4 acc[4][4], acc_a[4];
  #pragma unroll
  for (int mf = 0; mf < 4; mf++){
    acc_a[mf] = zero4;
    #pragma unroll
    for (int nf = 0; nf < 4; nf++) acc[mf][nf] = zero4;
  }
  #pragma unroll
  for (int kf = 0; kf < 4; kf++){
    int kb = kf * 32 + hi * 8;
    short8 a[4];
    #pragma unroll
    for (int mf = 0; mf < 4; mf++) a[mf] = *(const short8*)&aT[(mf * 16 + lo) * 136 + kb];
    #pragma unroll
    for (int mf = 0; mf < 4; mf++)
      #pragma unroll
      for (int nf = 0; nf < 4; nf++)
        acc[mf][nf] = __builtin_amdgcn_mfma_f32_16x16x32_bf16(a[mf], B[nf][kf], acc[mf][nf], 0, 0, 0);
    if (w == 0){
      #pragma unroll
      for (int mf = 0; mf < 4; mf++)
        acc_a[mf] = __builtin_amdgcn_mfma_f32_16x16x32_bf16(a[mf], WA[kf], acc_a[mf], 0, 0, 0);
    }
  }
  // stores
  #pragma unroll
  for (int mf = 0; mf < 4; mf++)
    #pragma unroll
    for (int rg = 0; rg < 4; rg++){
      int row = r0 + mf * 16 + hi * 4 + rg;
      #pragma unroll
      for (int nf = 0; nf < 4; nf++)
        h0[(size_t)row * C0 + w * 64 + nf * 16 + lo] = tbf(acc[mf][nf][rg]);
    }
  if (w == 0 && lo < 8){
    #pragma unroll
    for (int mf = 0; mf < 4; mf++)
      #pragma unroll
      for (int rg = 0; rg < 4; rg++){
        int row = r0 + mf * 16 + hi * 4 + rg;
        float v = acc_a[mf][rg];
        if (lo < 4) as0[row * H0_N + lo] = v;
        else if (row < N_DST0) ad0[row * H0_N + (lo - 4)] = v;
      }
  }
}

// ---------------- agg0: max pass + chunked LDS alphas + gather ----------------
__global__ __launch_bounds__(256) void agg0_kernel(
    const unsigned short* __restrict__ h0, const float* __restrict__ as0, const float* __restrict__ ad0,
    const int* __restrict__ row_ptr, const int* __restrict__ col,
    const float* __restrict__ bias0, unsigned short* __restrict__ out0)
{
  __shared__ f32x4 sp[4][64];
  __shared__ int   sc[4][64];
  int gid = blockIdx.x * 256 + threadIdx.x;
  int w = threadIdx.x >> 6;
  int d = gid >> 6, t = gid & 63;
  if (d >= N_DST0) return;
  int rs = row_ptr[d], re = row_ptr[d + 1];
  f32x4 adv = ((const f32x4*)ad0)[d];
  f32x4 asd = ((const f32x4*)as0)[d];
  f32x4 es;
  #pragma unroll
  for (int h = 0; h < 4; h++) es[h] = lrelu(asd[h] + adv[h]);

  // phase 1: max only
  f32x4 m4 = {-1e30f, -1e30f, -1e30f, -1e30f};
  for (int i = rs + t; i < re; i += 64){
    int s = col[i];
    f32x4 a4 = ((const f32x4*)as0)[s];
    #pragma unroll
    for (int h = 0; h < 4; h++) m4[h] = fmaxf(m4[h], lrelu(a4[h] + adv[h]));
  }
  #pragma unroll
  for (int msk = 1; msk < 64; msk <<= 1){
    #pragma unroll
    for (int h = 0; h < 4; h++) m4[h] = fmaxf(m4[h], __shfl_xor(m4[h], msk));
  }
  #pragma unroll
  for (int h = 0; h < 4; h++) m4[h] = fmaxf(m4[h], es[h]);

  int ht = t >> 4;
  float acc0 = 0.f, acc1 = 0.f, acc2 = 0.f, acc3 = 0.f;
  f32x4 zl = {0.f, 0.f, 0.f, 0.f};
  const float* spf = (const float*)sp;

  for (int c = rs; c < re; c += 64){
    int i = c + t;
    if (i < re){
      int s = col[i];
      f32x4 a4 = ((const f32x4*)as0)[s];
      f32x4 q4;
      #pragma unroll
      for (int h = 0; h < 4; h++){
        q4[h] = __expf(lrelu(a4[h] + adv[h]) - m4[h]);
        zl[h] += q4[h];
      }
      sp[w][t] = q4; sc[w][t] = s;
    }
    asm volatile("s_waitcnt lgkmcnt(0)" ::: "memory");
    int n = re - c; if (n > 64) n = 64;
    for (int j = 0; j < n; j++){
      int s = sc[w][j];
      float p = spf[(w * 64 + j) * 4 + ht];
      u16x4 hv = *(const u16x4*)&h0[(size_t)s * C0 + t * 4];
      acc0 += bf2f(hv[0]) * p; acc1 += bf2f(hv[1]) * p;
      acc2 += bf2f(hv[2]) * p; acc3 += bf2f(hv[3]) * p;
    }
    asm volatile("s_waitcnt lgkmcnt(0)" ::: "memory");
  }
  // z reduce + self loop
  #pragma unroll
  for (int msk = 1; msk < 64; msk <<= 1){
    #pragma unroll
    for (int h = 0; h < 4; h++) zl[h] += __shfl_xor(zl[h], msk);
  }
  #pragma unroll
  for (int h = 0; h < 4; h++) zl[h] += __expf(es[h] - m4[h]);
  float qs = __expf(es[ht] - m4[ht]);
  {
    u16x4 hv = *(const u16x4*)&h0[(size_t)d * C0 + t * 4];
    acc0 += bf2f(hv[0]) * qs; acc1 += bf2f(hv[1]) * qs;
    acc2 += bf2f(hv[2]) * qs; acc3 += bf2f(hv[3]) * qs;
  }
  float rz = 1.f / zl[ht];
  f32x4 b4 = ((const f32x4*)bias0)[t];
  uint2 pk;
  pk.x = pkt(acc0 * rz + b4[0], acc1 * rz + b4[1]);
  pk.y = pkt(acc2 * rz + b4[2], acc3 * rz + b4[3]);
  ((uint2*)out0)[(size_t)d * 64 + t] = pk;
}

// ---------------- BatchNorm stats (bf16 input) ----------------
__global__ void bn_stats(const unsigned short* __restrict__ out0, float* __restrict__ gsum, float* __restrict__ gsq){
  int t = threadIdx.x;
  int r0 = blockIdx.x * 128;
  int rend = r0 + 128; if (rend > N_DST0) rend = N_DST0;
  float s = 0.f, q = 0.f;
  for (int r = r0; r < rend; r++){
    float v = bf2f(out0[(size_t)r * C0 + t]);
    s += v; q += v * v;
  }
  atomicAdd(&gsum[t], s);
  atomicAdd(&gsq[t], q);
}

// ---------------- GEMM1: h1 = relu(bn(out0)) @ W1 + alpha; bn_final folded in ----------------
__global__ __launch_bounds__(256) void gemm1_kernel(
    const unsigned short* __restrict__ out0, const unsigned short* __restrict__ w1t,
    const unsigned short* __restrict__ wa1G,
    const float* __restrict__ gsum, const float* __restrict__ gsq,
    const float* __restrict__ gamma, const float* __restrict__ beta,
    float* __restrict__ h1, float* __restrict__ as1, float* __restrict__ ad1)
{
  __shared__ __align__(16) unsigned short aT[128 * 72];
  __shared__ __align__(16) unsigned short wT[48 * 72];
  __shared__ __align__(16) unsigned short wa1T[16 * 72];
  __shared__ float scL[C0], shL[C0];
  int tid = threadIdx.x;
  int r0 = blockIdx.x * 128;
  int w = tid >> 6, lane = tid & 63, lo = lane & 15, hi = lane >> 4;

  {
    float mu = gsum[tid] * (1.f / N_DST0);
    float var = gsq[tid] * (1.f / N_DST0) - mu * mu;
    float rs = rsqrtf(var + BN_EPS);
    float sc = gamma[tid] * rs;
    scL[tid] = sc;
    shL[tid] = beta[tid] - mu * sc;
  }
  __syncthreads();

  f32x4 zero4 = {0.f, 0.f, 0.f, 0.f};
  f32x4 acc[2][3], acc_a[2];
  #pragma unroll
  for (int mf = 0; mf < 2; mf++){
    acc_a[mf] = zero4;
    #pragma unroll
    for (int nf = 0; nf < 3; nf++) acc[mf][nf] = zero4;
  }

  for (int kc = 0; kc < 4; kc++){
    if (kc) __syncthreads();
    #pragma unroll
    for (int i = 0; i < 8; i++){
      int fi = tid + i * 256;          // 0..2047
      int row = fi >> 4, kq = fi & 15;
      int r = r0 + row;
      u16x4 v = {0,0,0,0};
      if (r < N_DST0) v = ((const u16x4*)out0)[(size_t)r * 64 + kc * 16 + kq];
      f32x4 sc4 = ((const f32x4*)scL)[kc * 16 + kq];
      f32x4 sh4 = ((const f32x4*)shL)[kc * 16 + kq];
      float f[4];
      #pragma unroll
      for (int j = 0; j < 4; j++){
        float u = bf2f(v[j]) * sc4[j] + sh4[j];
        f[j] = u > 0.f ? u : 0.f;
      }
      uint2 pk; pk.x = pkt(f[0], f[1]); pk.y = pkt(f[2], f[3]);
      *(uint2*)&aT[row * 72 + kq * 4] = pk;
    }
    #pragma unroll
    for (int i = 0; i < 3; i++){
      int fi = tid + i * 256;          // 0..767
      int n = fi >> 4, kq = fi & 15;
      *(u16x4*)&wT[n * 72 + kq * 4] = ((const u16x4*)w1t)[n * 64 + kc * 16 + kq];
    }
    {
      int n = tid >> 4, kq = tid & 15;
      u16x4 v = {0,0,0,0};
      if (n < 2) v = ((const u16x4*)wa1G)[n * 64 + kc * 16 + kq];
      *(u16x4*)&wa1T[n * 72 + kq * 4] = v;
    }
    __syncthreads();
    #pragma unroll
    for (int kk = 0; kk < 2; kk++){
      int kb = kk * 32 + hi * 8;
      short8 a[2], b[3];
      #pragma unroll
      for (int mf = 0; mf < 2; mf++) a[mf] = *(const short8*)&aT[(w * 32 + mf * 16 + lo) * 72 + kb];
      #pragma unroll
      for (int nf = 0; nf < 3; nf++) b[nf] = *(const short8*)&wT[(nf * 16 + lo) * 72 + kb];
      short8 wab = *(const short8*)&wa1T[lo * 72 + kb];
      #pragma unroll
      for (int mf = 0; mf < 2; mf++){
        #pragma unroll
        for (int nf = 0; nf < 3; nf++)
          acc[mf][nf] = __builtin_amdgcn_mfma_f32_16x16x32_bf16(a[mf], b[nf], acc[mf][nf], 0, 0, 0);
        acc_a[mf] = __builtin_amdgcn_mfma_f32_16x16x32_bf16(a[mf], wab, acc_a[mf], 0, 0, 0);
      }
    }
  }

  #pragma unroll
  for (int mf = 0; mf < 2; mf++)
    #pragma unroll
    for (int rg = 0; rg < 4; rg++){
      int r = r0 + w * 32 + mf * 16 + hi * 4 + rg;
      if (r < N_DST0){
        #pragma unroll
        for (int nf = 0; nf < 3; nf++)
          h1[(size_t)r * H1W + nf * 16 + lo] = acc[mf][nf][rg];
        if (lo == 0) as1[r] = acc_a[mf][rg];
        else if (lo == 1 && r < N_DST1) ad1[r] = acc_a[mf][rg];
      }
    }
}

// ---------------- agg1: max pass + chunked LDS alphas + gather + log_softmax ----------------
__global__ __launch_bounds__(256) void agg1_kernel(
    const float* __restrict__ h1, const float* __restrict__ as1, const float* __restrict__ ad1,
    const int* __restrict__ row_ptr, const int* __restrict__ col,
    const float* __restrict__ bias1, float* __restrict__ out)
{
  __shared__ float sp1[4][64];
  __shared__ int   sc1[4][64];
  int gid = blockIdx.x * 256 + threadIdx.x;
  int w = threadIdx.x >> 6;
  int d = gid >> 6, t = gid & 63;
  if (d >= N_DST1) return;
  int rs = row_ptr[N_DST0 + d], re = row_ptr[N_DST0 + d + 1];
  float adv = ad1[d];
  float es = lrelu(as1[d] + adv);
  float m = -1e30f;
  for (int i = rs + t; i < re; i += 64) m = fmaxf(m, lrelu(as1[col[i]] + adv));
  #pragma unroll
  for (int msk = 1; msk < 64; msk <<= 1) m = fmaxf(m, __shfl_xor(m, msk));
  m = fmaxf(m, es);

  bool tl = (t < H1W);
  float zl = 0.f, acc = 0.f;
  for (int c = rs; c < re; c += 64){
    int i = c + t;
    if (i < re){
      int s = col[i];
      float q = __expf(lrelu(as1[s] + adv) - m);
      zl += q;
      sp1[w][t] = q; sc1[w][t] = s;
    }
    asm volatile("s_waitcnt lgkmcnt(0)" ::: "memory");
    int n = re - c; if (n > 64) n = 64;
    for (int j = 0; j < n; j++){
      int s = sc1[w][j];
      float p = sp1[w][j];
      float hv = tl ? h1[(size_t)s * H1W + t] : 0.f;
      acc += p * hv;
    }
    asm volatile("s_waitcnt lgkmcnt(0)" ::: "memory");
  }
  #pragma unroll
  for (int msk = 1; msk < 64; msk <<= 1) zl += __shfl_xor(zl, msk);
  float qs = __expf(es - m);
  float z = zl + qs;
  float hs = tl ? h1[(size_t)d * H1W + t] : 0.f;
  acc = (acc + qs * hs) / z;
  float v = acc + ((t < OUTC) ? bias1[t] : 0.f);
  float vm = (t < OUTC) ? v : -1e30f;
  #pragma unroll
  for (int msk = 1; msk < 64; msk <<= 1) vm = fmaxf(vm, __shfl_xor(vm, msk));
  float ex = (t < OUTC) ? __expf(v - vm) : 0.f;
  #pragma unroll
  for (int msk = 1; msk < 64; msk <<= 1) ex += __shfl_xor(ex, msk);
  if (t < OUTC) out[(size_t)d * OUTC + t] = v - vm - __logf(ex);
}

// ---------------- launch ----------------
extern "C" void kernel_launch(void* const* d_in, const int* in_sizes, int n_in,
                              void* d_out, int out_size, void* d_ws, size_t ws_size,
                              hipStream_t stream)
{
  const float* x        = (const float*)d_in[0];
  const float* W0       = (const float*)d_in[1];
  const float* att_src0 = (const float*)d_in[2];
  const float* att_dst0 = (const float*)d_in[3];
  const float* bias0    = (const float*)d_in[4];
  const float* gamma0   = (const float*)d_in[5];
  const float* beta0    = (const float*)d_in[6];
  const float* W1       = (const float*)d_in[7];
  const float* att_src1 = (const float*)d_in[8];
  const float* att_dst1 = (const float*)d_in[9];
  const float* bias1    = (const float*)d_in[10];
  const int* esrc0 = (const int*)d_in[11];
  const int* edst0 = (const int*)d_in[12];
  const int* esrc1 = (const int*)d_in[13];
  const int* edst1 = (const int*)d_in[14];
  float* out = (float*)d_out;

  char* p = (char*)d_ws;
  auto alloc = [&](size_t b) -> char* {
    char* r = p; p += (b + 255) & ~(size_t)255; return r;
  };
  unsigned short* h0   = (unsigned short*)alloc((size_t)N_SRC * C0 * 2);    // 102.4 MB
  unsigned short* out0 = (unsigned short*)alloc((size_t)N_DST0 * C0 * 2);   // 25.6 MB
  unsigned short* wt0  = (unsigned short*)alloc((size_t)C0 * IN_C * 2);
  unsigned short* w1t  = (unsigned short*)alloc((size_t)H1W * C0 * 2);
  unsigned short* waG  = (unsigned short*)alloc((size_t)8 * IN_C * 2);
  unsigned short* wa1G = (unsigned short*)alloc((size_t)2 * C0 * 2);
  float* as0          = (float*)alloc((size_t)N_SRC * H0_N * 4);
  float* ad0          = (float*)alloc((size_t)N_DST0 * H0_N * 4);
  float* h1           = (float*)alloc((size_t)N_DST0 * H1W * 4);
  float* as1          = (float*)alloc((size_t)N_DST0 * 4);
  float* ad1          = (float*)alloc((size_t)N_DST1 * 4);
  int* row_ptr        = (int*)alloc((size_t)(NSEG + 1) * 4);
  int* cursor         = (int*)alloc((size_t)NSEG * 4);
  int* col            = (int*)alloc((size_t)E_TOT * 4);
  int* partials       = (int*)alloc((size_t)256 * 4);
  // contiguous zero zone
  char* zbase = p;
  int* cnt    = (int*)alloc((size_t)NSEG * 4);
  float* gsum = (float*)alloc((size_t)C0 * 4);
  float* gsq  = (float*)alloc((size_t)C0 * 4);
  size_t zspan = (size_t)(p - zbase);
  hipMemsetAsync(zbase, 0, zspan, stream);

  // K1: prep || hist
  prep_hist_kernel<<<dim3(NB_PREP + NB_HIST), 256, 0, stream>>>(
      W0, W1, att_src0, att_dst0, att_src1, att_dst1,
      wt0, w1t, waG, wa1G, edst0, edst1, cnt);

  scanA<<<dim3((NSEG + 255) / 256), 256, 0, stream>>>(cnt, partials);
  scanB<<<1, 256, 0, stream>>>(partials, (NSEG + 255) / 256);
  scanC<<<dim3((NSEG + 255) / 256), 256, 0, stream>>>(cnt, partials, row_ptr, cursor);

  // K2: gemm0 || scatter (independent; interleaved 5:7 for co-residency)
  gemm0_scatter_kernel<<<dim3(NB_GEMM + NB_SCAT), 256, 0, stream>>>(
      x, wt0, waG, h0, as0, ad0,
      esrc0, edst0, esrc1, edst1, cursor, col);

  agg0_kernel<<<dim3(N_DST0 / 4), 256, 0, stream>>>(h0, as0, ad0, row_ptr, col, bias0, out0);

  bn_stats<<<dim3((N_DST0 + 127) / 128), 256, 0, stream>>>(out0, gsum, gsq);

  gemm1_kernel<<<dim3((N_DST0 + 127) / 128), 256, 0, stream>>>(out0, w1t, wa1G,
                                                               gsum, gsq, gamma0, beta0,
                                                               h1, as1, ad1);

  agg1_kernel<<<dim3(N_DST1 / 4), 256, 0, stream>>>(h1, as1, ad1, row_ptr, col, bias1, out);
}